// Round 5
// baseline (3260.486 us; speedup 1.0000x reference)
//
#include <hip/hip_runtime.h>
#include <math.h>

#define BB 4
#define N0 4096
#define NEWP 1152
#define GD 256
#define HD 128
#define KSEL 64
#define NSTEPS 10
#define NMAX (N0 + NSTEPS*NEWP)   /* 15616 */
#define NNEW (NSTEPS*NEWP)        /* 11520 */

#define NBLK 256
#define NTHR 1024

/* ---- workspace layout (float offsets) ---- */
#define OFF_CANVAS 0
#define OFF_MINAB  (OFF_CANVAS + BB*NMAX*3)
#define OFF_MINCD  (OFF_MINAB + 2*BB*N0)
#define OFF_GMAX   (OFF_MINCD + BB*NNEW + BB*N0)
#define OFF_H      (OFF_GMAX + BB*GD)
#define OFF_C      (OFF_H + 2*BB*HD)
#define OFF_ACC    (OFF_C + 2*BB*HD)
#define OFF_CENTER (OFF_ACC + 16)
#define OFF_PART   (OFF_CENTER + 32)
#define OFF_GPRE   (OFF_PART + BB*32*8)      /* 4*512 gate partials */

#define AGT __HIP_MEMORY_SCOPE_AGENT

/* coherent (cache-bypassing, IF-coherence-point) accessors for cross-block
   data. Weights/inputs keep normal cached loads. */
__device__ __forceinline__ float cld(const float* p){
  return __hip_atomic_load((float*)p, __ATOMIC_RELAXED, AGT);
}
__device__ __forceinline__ void cst(float* p, float v){
  __hip_atomic_store(p, v, __ATOMIC_RELAXED, AGT);
}
__device__ __forceinline__ unsigned culd(const unsigned* p){
  return __hip_atomic_load((unsigned*)p, __ATOMIC_RELAXED, AGT);
}
__device__ __forceinline__ void cust(unsigned* p, unsigned v){
  __hip_atomic_store(p, v, __ATOMIC_RELAXED, AGT);
}
__device__ __forceinline__ float ldc(const float* p, bool coh){
  return coh ? cld(p) : *p;
}

__device__ __forceinline__ unsigned enc_f(float f){
  unsigned u = __float_as_uint(f);
  return (u & 0x80000000u) ? ~u : (u | 0x80000000u);
}
__device__ __forceinline__ float dec_f(unsigned e){
  unsigned u = (e & 0x80000000u) ? (e & 0x7fffffffu) : ~e;
  return __uint_as_float(u);
}
__device__ __forceinline__ float sigm(float x){ return 1.f/(1.f+expf(-x)); }

__device__ __forceinline__ float block_sum(float v, volatile float* red){
#pragma unroll
  for (int s=32;s>0;s>>=1) v += __shfl_down(v, s, 64);
  int lane = threadIdx.x & 63, w = threadIdx.x >> 6, nw = blockDim.x >> 6;
  __syncthreads();
  if (lane==0) red[w] = v;
  __syncthreads();
  if (w==0){
    float x = (lane < nw) ? red[lane] : 0.f;
#pragma unroll
    for (int s=8;s>0;s>>=1) x += __shfl_down(x, s, 64);
    if (lane==0) red[0] = x;
  }
  __syncthreads();
  float r = red[0];
  __syncthreads();
  return r;
}
__device__ __forceinline__ float block_max(float v, volatile float* red){
#pragma unroll
  for (int s=32;s>0;s>>=1) v = fmaxf(v, __shfl_down(v, s, 64));
  int lane = threadIdx.x & 63, w = threadIdx.x >> 6, nw = blockDim.x >> 6;
  __syncthreads();
  if (lane==0) red[w] = v;
  __syncthreads();
  if (w==0){
    float x = (lane < nw) ? red[lane] : -3.4e38f;
#pragma unroll
    for (int s=8;s>0;s>>=1) x = fmaxf(x, __shfl_down(x, s, 64));
    if (lane==0) red[0] = x;
  }
  __syncthreads();
  float r = red[0];
  __syncthreads();
  return r;
}

/* ---- fence-free grid barrier: 2-level monotonic arrive/spin.
   s_sleep(32) backoff keeps spin fetch ~19 GB/s (proven r4). ---- */
__device__ __align__(128) unsigned g_grp[256];   /* 8 counters, stride 32 */
__device__ __align__(128) unsigned g_root;
__device__ __align__(128) unsigned g_gen;

__device__ __forceinline__ void gsync(){
  __syncthreads();
  if (threadIdx.x == 0){
    unsigned snap = __hip_atomic_load(&g_gen, __ATOMIC_RELAXED, AGT);
    asm volatile("" ::: "memory");
    int g = blockIdx.x >> 5;
    unsigned od = __hip_atomic_fetch_add(&g_grp[g*32], 1u, __ATOMIC_RELAXED, AGT);
    bool done = false;
    if ((od & 31u) == 31u){
      unsigned rd = __hip_atomic_fetch_add(&g_root, 1u, __ATOMIC_RELAXED, AGT);
      if ((rd & 7u) == 7u){
        __hip_atomic_fetch_add(&g_gen, 1u, __ATOMIC_RELAXED, AGT);
        done = true;
      }
    }
    if (!done){
      while (__hip_atomic_load(&g_gen, __ATOMIC_RELAXED, AGT) == snap)
        __builtin_amdgcn_s_sleep(32);
    }
    asm volatile("" ::: "memory");
  }
  __syncthreads();
}

/* one 16KB shared-memory arena, aliased per phase */
struct alignas(16) SU {
  union {
    struct { float sy0[1024], sy1[1024], sy2[1024], sny[1024]; } ch;
    struct { float sBatt[128]; float sGH[GD+HD]; float red[16]; } sl;
    struct { float red[16]; float sC[3]; unsigned cbufA[2][16]; unsigned cbufB[2][16];
             int tieCnt; int tieIdx[256]; } sa;
    struct { float sG[512]; float sH[HD]; float sRf[HD]; } re;
    struct { float red[16]; } rd;
  } u;
};

/* fused enc1->enc2->enc3 for one point, 16-dim chunk at d0.
   enc2 computed in k-tiles of 16 held in registers: j-outer loop reads
   w2[j][k0..k0+15] (one 64B line, wave-uniform) and FMAs into 16
   INDEPENDENT accumulators (breaks the 64-deep serial chain of r4 and
   fixes the 1-line-per-FMA column walk). Summation orders (f2: j=0..63,
   f3: k=0..127) are bitwise-identical to r4. Live set ~111 regs. */
__device__ __forceinline__ void enc123_point(
    float p0, float p1, float p2, int d0,
    const float* __restrict__ w1, const float* __restrict__ b1,
    const float* __restrict__ w2, const float* __restrict__ b2,
    const float* __restrict__ w3, const float* __restrict__ b3,
    bool act, unsigned* gmaxrow, int tid)
{
  float f1[64];
#pragma unroll
  for (int j=0;j<64;j++)
    f1[j] = fmaxf(0.f, b1[j] + p0*w1[j] + p1*w1[64+j] + p2*w1[128+j]);
  float accd[16];
#pragma unroll
  for (int c=0;c<16;c++) accd[c] = b3[d0 + c];
#pragma unroll 1
  for (int k0=0;k0<128;k0+=16){
    float sacc[16];
#pragma unroll
    for (int kk=0;kk<16;kk++) sacc[kk] = b2[k0+kk];
#pragma unroll
    for (int j=0;j<64;j++){
      const float* wr = w2 + j*128 + k0;     /* 64B line, wave-uniform */
      float fj = f1[j];
#pragma unroll
      for (int kk=0;kk<16;kk++) sacc[kk] = fmaf(fj, wr[kk], sacc[kk]);
    }
#pragma unroll
    for (int kk=0;kk<16;kk++){
      float fv = fmaxf(sacc[kk], 0.f);
      const float* wr3 = w3 + (size_t)(k0+kk)*256 + d0;  /* 64B line */
#pragma unroll
      for (int c=0;c<16;c++) accd[c] = fmaf(fv, wr3[c], accd[c]);
    }
  }
#pragma unroll
  for (int c=0;c<16;c++){
    float v = act ? accd[c] : -3.4e38f;
#pragma unroll
    for (int s2=32;s2>0;s2>>=1) v = fmaxf(v, __shfl_down(v, s2, 64));
    if ((tid & 63) == 0) atomicMax(&gmaxrow[d0 + c], enc_f(v));
  }
}

/* one chamfer tile; min chain split in two (min is order-independent) */
template<int QN>
__device__ __forceinline__ void chamfer_tile(
    const float* X, const float* Y, unsigned* mp,
    int Nx, int xbase, int tn, bool xcv, bool ycv,
    float* sy0, float* sy1, float* sy2, float* sny, int tid)
{
  for (int tt=tid; tt<tn; tt+=NTHR){
    const float* yp = Y + (size_t)tt*3;
    float y0=ldc(yp,ycv), y1=ldc(yp+1,ycv), y2=ldc(yp+2,ycv);
    sy0[tt]=-2.f*y0; sy1[tt]=-2.f*y1; sy2[tt]=-2.f*y2;
    sny[tt]=y0*y0+y1*y1+y2*y2;
  }
  __syncthreads();
  float X0[QN],X1[QN],X2[QN],NXr[QN],MNa[QN],MNb[QN]; int XI[QN]; bool VA[QN];
#pragma unroll
  for (int q=0;q<QN;q++){
    int x = xbase + q*NTHR + tid;
    VA[q] = x < Nx;
    int xc = VA[q] ? x : 0;
    const float* xp = X + (size_t)xc*3;
    X0[q]=ldc(xp,xcv); X1[q]=ldc(xp+1,xcv); X2[q]=ldc(xp+2,xcv);
    NXr[q] = X0[q]*X0[q] + X1[q]*X1[q] + X2[q]*X2[q];
    MNa[q] = 3.4e38f; MNb[q] = 3.4e38f; XI[q] = xc;
  }
  const float4* v0 = (const float4*)sy0;
  const float4* v1 = (const float4*)sy1;
  const float4* v2 = (const float4*)sy2;
  const float4* vn = (const float4*)sny;
  int j4n = tn >> 2;
  for (int j=0;j<j4n;j++){
    float4 a0 = v0[j], a1 = v1[j], a2 = v2[j], an = vn[j];
#pragma unroll
    for (int e=0;e<4;e++){
      float y0 = ((const float*)&a0)[e];
      float y1 = ((const float*)&a1)[e];
      float y2 = ((const float*)&a2)[e];
      float ny = ((const float*)&an)[e];
#pragma unroll
      for (int q=0;q<QN;q++){
        float d = fmaf(X0[q], y0, fmaf(X1[q], y1, fmaf(X2[q], y2, ny)));
        if (e & 1) MNb[q] = fminf(MNb[q], d);
        else       MNa[q] = fminf(MNa[q], d);
      }
    }
  }
  for (int j=j4n*4; j<tn; j++){
    float y0=sy0[j], y1=sy1[j], y2=sy2[j], ny=sny[j];
#pragma unroll
    for (int q=0;q<QN;q++){
      float d = fmaf(X0[q], y0, fmaf(X1[q], y1, fmaf(X2[q], y2, ny)));
      MNa[q] = fminf(MNa[q], d);
    }
  }
#pragma unroll
  for (int q=0;q<QN;q++)
    if (VA[q]) atomicMin(&mp[XI[q]], enc_f(fminf(MNa[q], MNb[q]) + NXr[q]));
}

__global__ __attribute__((amdgpu_flat_work_group_size(NTHR,NTHR), amdgpu_waves_per_eu(4,4)))
void mega_kernel(
    const float* __restrict__ points, const float* __restrict__ gt,
    const float* __restrict__ w1,  const float* __restrict__ b1,
    const float* __restrict__ w2,  const float* __restrict__ b2,
    const float* __restrict__ w3,  const float* __restrict__ b3,
    const float* __restrict__ aw1, const float* __restrict__ ab1,
    const float* __restrict__ aw2, const float* __restrict__ ab2,
    const float* __restrict__ wih, const float* __restrict__ whh,
    const float* __restrict__ bih, const float* __restrict__ bhh,
    const float* __restrict__ rw1, const float* __restrict__ rb1,
    const float* __restrict__ rw2, const float* __restrict__ rb2,
    float* __restrict__ out, float* __restrict__ ws)
{
  __shared__ SU su;
  const int tid = threadIdx.x;
  const int blk = blockIdx.x;

  float* canvas   = ws + OFF_CANVAS;
  unsigned* minAB = (unsigned*)(ws + OFF_MINAB);
  unsigned* minCD = (unsigned*)(ws + OFF_MINCD);
  unsigned* gmax  = (unsigned*)(ws + OFF_GMAX);
  float* hb       = ws + OFF_H;
  float* cb       = ws + OFF_C;
  float* acc      = ws + OFF_ACC;
  float* centerb  = ws + OFF_CENTER;
  float* partb    = ws + OFF_PART;
  float* gpre     = ws + OFF_GPRE;

  /* ============ P0: init ============ */
  {
    int gid = blk*NTHR + tid;
    if (gid < BB*N0*3){
      int b = gid/(N0*3), r = gid - b*(N0*3);
      cst(&canvas[(size_t)b*NMAX*3 + r], points[gid]);
    }
    if (gid < 2*BB*N0) cust(&minAB[gid], 0xFFFFFFFFu);
    if (gid < BB*NNEW + BB*N0) cust(&minCD[gid], 0xFFFFFFFFu);
    if (gid < BB*GD) cust(&gmax[gid], 0u);
    if (gid < 2*BB*HD){ cst(&hb[gid], 0.f); cst(&cb[gid], 0.f); }
  }
  gsync();

  /* ============ P1: fused enc123 + max-pool of the 16384 initial points.
     256 blocks = 16 point-groups x 16 d-groups (16 dims each). ============ */
  {
    int ptg = blk >> 4, dcg = blk & 15;
    int gp = ptg*NTHR + tid;           /* 0..16383 */
    int b  = gp >> 12;
    const float* p = points + (size_t)gp*3;
    float p0 = p[0], p1 = p[1], p2 = p[2];
    enc123_point(p0, p1, p2, dcg*16, w1, b1, w2, b2, w3, b3,
                 true, &gmax[b*GD], tid);
  }
  gsync();

  /* ============ 10-step loop ============ */
  for (int t=0; t<NSTEPS; t++){
    int N   = N0 + t*NEWP;
    int nch = (N + NTHR-1) >> 10;      /* chunks of 1024 */
    float* h_in  = hb + (t&1)*BB*HD;
    float* h_out = hb + ((t+1)&1)*BB*HD;
    float* c_in  = cb + (t&1)*BB*HD;
    float* c_out = cb + ((t+1)&1)*BB*HD;

    /* ---- SL phase: attention partials (blocks 0..4nch-1, <=60)
            + LSTM gate precompute (blocks 252..255) ---- */
    if (blk < 4*nch){
      int b = blk / nch, ch = blk - b*nch;
      if (tid < GD+HD)
        su.u.sl.sGH[tid] = (tid < GD) ? dec_f(culd(&gmax[b*GD + tid]))
                                      : cld(&h_in[b*HD + (tid-GD)]);
      __syncthreads();
      if (tid < 128){
        float a0=0.f,a1=0.f,a2=0.f,a3=0.f;
        for (int k=0;k<GD+HD;k+=4){
          a0 = fmaf(su.u.sl.sGH[k  ], aw1[(3+k  )*128 + tid], a0);
          a1 = fmaf(su.u.sl.sGH[k+1], aw1[(4+k  )*128 + tid], a1);
          a2 = fmaf(su.u.sl.sGH[k+2], aw1[(5+k  )*128 + tid], a2);
          a3 = fmaf(su.u.sl.sGH[k+3], aw1[(6+k  )*128 + tid], a3);
        }
        su.u.sl.sBatt[tid] = ab1[tid] + ((a0+a1)+(a2+a3));
      }
      __syncthreads();
      int i = ch*NTHR + tid;
      bool act = i < N;
      float p0=0.f,p1=0.f,p2=0.f,s=-3.4e38f;
      if (act){
        const float* pp = canvas + (size_t)(b*NMAX + i)*3;
        p0=cld(pp); p1=cld(pp+1); p2=cld(pp+2);
        float s0=0.f,s1=0.f,s2=0.f,s3=0.f;
        for (int j=0;j<128;j+=4){
          float v0 = su.u.sl.sBatt[j  ] + p0*aw1[j  ] + p1*aw1[128+j  ] + p2*aw1[256+j  ];
          float v1 = su.u.sl.sBatt[j+1] + p0*aw1[j+1] + p1*aw1[128+j+1] + p2*aw1[256+j+1];
          float v2 = su.u.sl.sBatt[j+2] + p0*aw1[j+2] + p1*aw1[128+j+2] + p2*aw1[256+j+2];
          float v3 = su.u.sl.sBatt[j+3] + p0*aw1[j+3] + p1*aw1[128+j+3] + p2*aw1[256+j+3];
          s0 = fmaf(fmaxf(v0,0.f), aw2[j  ], s0);
          s1 = fmaf(fmaxf(v1,0.f), aw2[j+1], s1);
          s2 = fmaf(fmaxf(v2,0.f), aw2[j+2], s2);
          s3 = fmaf(fmaxf(v3,0.f), aw2[j+3], s3);
        }
        s = ab2[0] + ((s0+s1)+(s2+s3));
      }
      float mb = block_max(s, su.u.sl.red);
      float e = act ? expf(s - mb) : 0.f;
      float se = block_sum(e, su.u.sl.red);
      float wx = block_sum(e*p0, su.u.sl.red);
      float wy = block_sum(e*p1, su.u.sl.red);
      float wz = block_sum(e*p2, su.u.sl.red);
      if (tid==0){
        float* pr = partb + (size_t)(b*32 + ch)*8;
        cst(pr+0, mb); cst(pr+1, se); cst(pr+2, wx); cst(pr+3, wy); cst(pr+4, wz);
      }
    } else if (blk >= 252){
      int b = blk - 252;
      if (tid < GD+HD)
        su.u.sl.sGH[tid] = (tid < GD) ? dec_f(culd(&gmax[b*GD + tid]))
                                      : cld(&h_in[b*HD + (tid-GD)]);
      __syncthreads();
      if (tid < 512){
        int o = tid;
        float g0=0.f,g1=0.f,g2=0.f,g3=0.f;
        for (int k=0;k<GD;k+=4){
          g0 = fmaf(su.u.sl.sGH[k  ], wih[(size_t)(k  )*512 + o], g0);
          g1 = fmaf(su.u.sl.sGH[k+1], wih[(size_t)(k+1)*512 + o], g1);
          g2 = fmaf(su.u.sl.sGH[k+2], wih[(size_t)(k+2)*512 + o], g2);
          g3 = fmaf(su.u.sl.sGH[k+3], wih[(size_t)(k+3)*512 + o], g3);
        }
        for (int k=0;k<HD;k+=4){
          g0 = fmaf(su.u.sl.sGH[GD+k  ], whh[(size_t)(k  )*512 + o], g0);
          g1 = fmaf(su.u.sl.sGH[GD+k+1], whh[(size_t)(k+1)*512 + o], g1);
          g2 = fmaf(su.u.sl.sGH[GD+k+2], whh[(size_t)(k+2)*512 + o], g2);
          g3 = fmaf(su.u.sl.sGH[GD+k+3], whh[(size_t)(k+3)*512 + o], g3);
        }
        cst(&gpre[b*512 + o], bih[o] + bhh[o] + ((g0+g1)+(g2+g3)));
      }
    }
    gsync();

    /* ---- stepA phase: center+top-K (blocks 0..3, 1024 thr)
            + incremental chamfer in otherwise-idle blocks ---- */
    if (blk < 4){
      int b = blk;
      const float* cv = canvas + (size_t)b*NMAX*3;
      int lane = tid & 63, wid = tid >> 6;

      float pm=-3.4e38f, pse=0.f, pwx=0.f, pwy=0.f, pwz=0.f;
      if (tid < nch){
        const float* pp = partb + (size_t)(b*32 + tid)*8;
        pm=cld(pp); pse=cld(pp+1); pwx=cld(pp+2); pwy=cld(pp+3); pwz=cld(pp+4);
      }
      float M = block_max(pm, su.u.sa.red);
      float w = (tid < nch) ? expf(pm - M) : 0.f;
      float se = block_sum(pse*w, su.u.sa.red);
      float wx = block_sum(pwx*w, su.u.sa.red);
      float wy = block_sum(pwy*w, su.u.sa.red);
      float wz = block_sum(pwz*w, su.u.sa.red);
      if (tid==0){ su.u.sa.sC[0]=wx/se; su.u.sa.sC[1]=wy/se; su.u.sa.sC[2]=wz/se; }
      __syncthreads();
      float cx=su.u.sa.sC[0], cy=su.u.sa.sC[1], cz=su.u.sa.sC[2];
      if (tid<3) cst(&centerb[b*3+tid], su.u.sa.sC[tid]);

      unsigned ur[16];
#pragma unroll
      for (int q=0;q<16;q+=8){
        float px[8], py[8], pz[8];
#pragma unroll
        for (int r=0;r<8;r++){
          int i = tid + (q+r)*NTHR;
          int ic2 = (i < N) ? i : 0;
          const float* p = cv + (size_t)ic2*3;
          px[r]=cld(p); py[r]=cld(p+1); pz[r]=cld(p+2);
        }
#pragma unroll
        for (int r=0;r<8;r++){
          int i = tid + (q+r)*NTHR;
          ur[q+r] = 0xFFFFFFFFu;
          if (i < N){
            float dx=px[r]-cx, dy=py[r]-cy, dz=pz[r]-cz;
            ur[q+r] = __float_as_uint(dx*dx + dy*dy + dz*dz);
          }
        }
      }

      unsigned T = 0u;
      int cntBelow = 0;
      int par = 0;
      {
        unsigned cand = 1u<<30;
        unsigned tc = 0;
#pragma unroll
        for (int q=0;q<16;q++) tc += (ur[q] < cand) ? 1u : 0u;
#pragma unroll
        for (int s2=32;s2>0;s2>>=1) tc += __shfl_down(tc, s2, 64);
        if (lane==0) su.u.sa.cbufA[par][wid] = tc;
        __syncthreads();
        unsigned tot = 0;
#pragma unroll
        for (int i2=0;i2<16;i2++) tot += su.u.sa.cbufA[par][i2];
        if ((int)tot < KSEL){ T = cand; cntBelow = (int)tot; }
        par ^= 1;
      }
      for (int bit=29; bit>=1; bit-=2){
        unsigned q1 = 1u<<(bit-1);
        unsigned c1 = T + q1, c2 = T + 2u*q1, c3 = T + 3u*q1;
        unsigned ta = 0, tb = 0;
#pragma unroll
        for (int q=0;q<16;q++){
          unsigned u = ur[q];
          ta += (u < c1 ? 1u : 0u) | (u < c2 ? 0x10000u : 0u);
          tb += (u < c3 ? 1u : 0u);
        }
#pragma unroll
        for (int s2=32;s2>0;s2>>=1){ ta += __shfl_down(ta, s2, 64); tb += __shfl_down(tb, s2, 64); }
        if (lane==0){ su.u.sa.cbufA[par][wid] = ta; su.u.sa.cbufB[par][wid] = tb; }
        __syncthreads();
        unsigned sa2 = 0, sb2 = 0;
#pragma unroll
        for (int i2=0;i2<16;i2++){ sa2 += su.u.sa.cbufA[par][i2]; sb2 += su.u.sa.cbufB[par][i2]; }
        int n1 = (int)(sa2 & 0xFFFFu), n2 = (int)(sa2 >> 16), n3 = (int)sb2;
        if (n3 < KSEL){ T = c3; cntBelow = n3; }
        else if (n2 < KSEL){ T = c2; cntBelow = n2; }
        else if (n1 < KSEL){ T = c1; cntBelow = n1; }
        par ^= 1;
      }
      int kneed = KSEL - cntBelow;

      if (tid==0) su.u.sa.tieCnt = 0;
      __syncthreads();
      float sx=0.f, sy=0.f, sz=0.f;
#pragma unroll
      for (int q=0;q<16;q++){
        unsigned uu = ur[q];
        if (uu < T){
          const float* p = cv + (size_t)(tid + q*NTHR)*3;
          sx += cld(p); sy += cld(p+1); sz += cld(p+2);
        } else if (uu == T){
          int pos = atomicAdd(&su.u.sa.tieCnt, 1);
          if (pos < 256) su.u.sa.tieIdx[pos] = tid + q*NTHR;
        }
      }
      __syncthreads();
      sx = block_sum(sx, su.u.sa.red);
      sy = block_sum(sy, su.u.sa.red);
      sz = block_sum(sz, su.u.sa.red);
      if (tid==0){
        int mm = su.u.sa.tieCnt < 256 ? su.u.sa.tieCnt : 256;
        for (int tt=0; tt<kneed; tt++){
          int best=-1, bi=0x7fffffff;
          for (int q=0;q<mm;q++){ int v = su.u.sa.tieIdx[q]; if (v < bi){ bi=v; best=q; } }
          if (best >= 0){
            su.u.sa.tieIdx[best] = 0x7fffffff;
            const float* p = cv + (size_t)bi*3;
            sx += cld(p); sy += cld(p+1); sz += cld(p+2);
          }
        }
        cst(&centerb[16 + b*3 + 0], sx/KSEL - cx);
        cst(&centerb[16 + b*3 + 1], sy/KSEL - cy);
        cst(&centerb[16 + b*3 + 2], sz/KSEL - cz);
      }
    } else if (t == 0 && blk < 68){
      /* dir0: canvas[0..N0) -> gt. 64 blocks, QN=1. */
      int rem = blk - 4;
      int b = rem >> 4, l = rem & 15, xb = l >> 2, yb = l & 3;
      chamfer_tile<1>(canvas + (size_t)b*NMAX*3, gt + ((size_t)b*N0 + yb*1024)*3,
                      minAB + b*N0, N0, xb*1024, 1024, true, false,
                      su.u.ch.sy0, su.u.ch.sy1, su.u.ch.sy2, su.u.ch.sny, tid);
    } else if (t >= 1 && blk < 20){
      /* dir2 incremental: new points of step t-1 -> gt. 16 blocks. */
      int rem = blk - 4;
      int b = rem >> 2, yb = rem & 3;
      chamfer_tile<2>(canvas + ((size_t)b*NMAX + N0 + (size_t)(t-1)*NEWP)*3,
                      gt + ((size_t)b*N0 + yb*1024)*3,
                      minCD + b*NNEW + (t-1)*NEWP, NEWP, 0, 1024, true, false,
                      su.u.ch.sy0, su.u.ch.sy1, su.u.ch.sy2, su.u.ch.sny, tid);
    }
    gsync();

    /* ---- REF phase: LSTM finish + refine-decode + canvas append
            + fused enc123 of the new points (blocks 0..127) ---- */
    if (blk < 128){
      int bx = blk >> 6, b = (blk >> 4) & 3, dcg = blk & 15;  /* 2*4*16 */
      float cx = cld(&centerb[b*3+0]), cy = cld(&centerb[b*3+1]), cz = cld(&centerb[b*3+2]);
      float fx = cld(&centerb[16+b*3+0]), fy = cld(&centerb[16+b*3+1]), fz = cld(&centerb[16+b*3+2]);
      if (tid < 512){
        int o = tid;
        float gg = cld(&gpre[b*512 + o]);
        gg += cx*wih[(size_t)256*512+o] + cy*wih[(size_t)257*512+o] + cz*wih[(size_t)258*512+o];
        gg += fx*wih[(size_t)259*512+o] + fy*wih[(size_t)260*512+o] + fz*wih[(size_t)261*512+o];
        su.u.re.sG[o] = gg;
      }
      __syncthreads();
      if (tid < HD){
        float gi=su.u.re.sG[tid], gf=su.u.re.sG[128+tid], gg2=su.u.re.sG[256+tid], go=su.u.re.sG[384+tid];
        float cn = sigm(gf)*cld(&c_in[b*HD+tid]) + sigm(gi)*tanhf(gg2);
        float hn = sigm(go)*tanhf(cn);
        su.u.re.sH[tid] = hn;
        if (bx==0 && dcg==0){ cst(&c_out[b*HD+tid], cn); cst(&h_out[b*HD+tid], hn); }
      }
      __syncthreads();
      if (tid < HD){
        float a0=0.f,a1=0.f,a2=0.f,a3=0.f;
        for (int k=0;k<HD;k+=4){
          a0 = fmaf(su.u.re.sH[k  ], rw1[(k  )*HD + tid], a0);
          a1 = fmaf(su.u.re.sH[k+1], rw1[(k+1)*HD + tid], a1);
          a2 = fmaf(su.u.re.sH[k+2], rw1[(k+2)*HD + tid], a2);
          a3 = fmaf(su.u.re.sH[k+3], rw1[(k+3)*HD + tid], a3);
        }
        su.u.re.sRf[tid] = fmaxf(rb1[tid] + ((a0+a1)+(a2+a3)), 0.f);
      }
      __syncthreads();
      int i = bx*NTHR + tid;
      bool act = i < NEWP;
      int ic = act ? i : 0;
      float a0 = rb2[3*ic], a1 = rb2[3*ic+1], a2 = rb2[3*ic+2];
      for (int k=0;k<HD;k++){
        const float* wv = rw2 + (size_t)k*(NEWP*3) + 3*ic;
        float hk = su.u.re.sRf[k];
        a0 = fmaf(hk, wv[0], a0); a1 = fmaf(hk, wv[1], a1); a2 = fmaf(hk, wv[2], a2);
      }
      float p0 = fmaf(a0, 0.02f, cx), p1 = fmaf(a1, 0.02f, cy), p2 = fmaf(a2, 0.02f, cz);
      if (act && dcg==0){
        float* cp = canvas + ((size_t)b*NMAX + N + i)*3;
        cst(cp+0, p0); cst(cp+1, p1); cst(cp+2, p2);
      }
      if (t < NSTEPS-1){
        enc123_point(p0, p1, p2, dcg*16, w1, b1, w2, b2, w3, b3,
                     act, &gmax[b*GD], tid);
      }
    }
    gsync();
  }

  /* ============ final chamfer: dir1 (128), dir3 (96), dir2-last (16) ==== */
  {
    if (blk < 128){
      int b = blk >> 5, l = blk & 31, xb = l >> 4, yb = l & 15;
      int tn = min(1024, NMAX - yb*1024);
      chamfer_tile<2>(gt + (size_t)b*N0*3, canvas + ((size_t)b*NMAX + yb*1024)*3,
                      minAB + BB*N0 + b*N0, N0, xb*2048, tn, false, true,
                      su.u.ch.sy0, su.u.ch.sy1, su.u.ch.sy2, su.u.ch.sny, tid);
    } else if (blk < 224){
      int rem = blk - 128;
      int b = rem/24, l = rem%24, xb = l/12, yb = l%12;
      int tn = min(1024, NNEW - yb*1024);
      chamfer_tile<2>(gt + (size_t)b*N0*3, canvas + ((size_t)b*NMAX + N0 + yb*1024)*3,
                      minCD + BB*NNEW + b*N0, N0, xb*2048, tn, false, true,
                      su.u.ch.sy0, su.u.ch.sy1, su.u.ch.sy2, su.u.ch.sny, tid);
    } else if (blk < 240){
      int rem = blk - 224;
      int b = rem >> 2, yb = rem & 3;
      chamfer_tile<2>(canvas + ((size_t)b*NMAX + N0 + (size_t)(NSTEPS-1)*NEWP)*3,
                      gt + ((size_t)b*N0 + yb*1024)*3,
                      minCD + b*NNEW + (NSTEPS-1)*NEWP, NEWP, 0, 1024, true, false,
                      su.u.ch.sy0, su.u.ch.sy1, su.u.ch.sy2, su.u.ch.sny, tid);
    }
  }
  gsync();

  /* ============ reduce (blocks 0..15) ============ */
  if (blk < 16){
    int s = blk, dir = s>>2, b = s&3;
    const unsigned* mp; int len;
    if (dir==0){      mp=minAB + b*N0;            len=N0; }
    else if (dir==1){ mp=minAB + BB*N0 + b*N0;    len=N0; }
    else if (dir==2){ mp=minCD + b*NNEW;          len=NNEW; }
    else {            mp=minCD + BB*NNEW + b*N0;  len=N0; }
    float v = 0.f;
    int i = tid;
    for (; i + 3*NTHR < len; i += 4*NTHR){
      unsigned u0=culd(mp+i), u1=culd(mp+i+NTHR), u2=culd(mp+i+2*NTHR), u3=culd(mp+i+3*NTHR);
      v += dec_f(u0); v += dec_f(u1); v += dec_f(u2); v += dec_f(u3);
    }
    for (; i < len; i += NTHR) v += dec_f(culd(mp+i));
    v = block_sum(v, su.u.rd.red);
    if (tid==0) cst(&acc[s], v);
  }
  gsync();

  /* ============ finish ============ */
  if (blk == 0 && tid == 0){
    float cd1 = 0.f, cd2 = 0.f;
    for (int b=0;b<BB;b++) cd1 += cld(&acc[b])/(float)N0 + cld(&acc[4+b])/(float)N0;
    for (int b=0;b<BB;b++) cd2 += cld(&acc[8+b])/(float)NNEW + cld(&acc[12+b])/(float)N0;
    out[0] = 0.1f*(cd1/BB) + 1.0f*(cd2/BB);
  }
}

extern "C" void kernel_launch(void* const* d_in, const int* in_sizes, int n_in,
                              void* d_out, int out_size, void* d_ws, size_t ws_size,
                              hipStream_t stream) {
  (void)in_sizes; (void)n_in; (void)out_size; (void)ws_size;
  const float* points   = (const float*)d_in[0];
  const float* gt       = (const float*)d_in[1];
  const float* enc_w1   = (const float*)d_in[2];
  const float* enc_b1   = (const float*)d_in[3];
  const float* enc_w2   = (const float*)d_in[4];
  const float* enc_b2   = (const float*)d_in[5];
  const float* enc_w3   = (const float*)d_in[6];
  const float* enc_b3   = (const float*)d_in[7];
  const float* att_w1   = (const float*)d_in[8];
  const float* att_b1   = (const float*)d_in[9];
  const float* att_w2   = (const float*)d_in[10];
  const float* att_b2   = (const float*)d_in[11];
  const float* lstm_wih = (const float*)d_in[12];
  const float* lstm_whh = (const float*)d_in[13];
  const float* lstm_bih = (const float*)d_in[14];
  const float* lstm_bhh = (const float*)d_in[15];
  const float* ref_w1   = (const float*)d_in[16];
  const float* ref_b1   = (const float*)d_in[17];
  const float* ref_w2   = (const float*)d_in[18];
  const float* ref_b2   = (const float*)d_in[19];
  float* out = (float*)d_out;
  float* ws  = (float*)d_ws;

  mega_kernel<<<dim3(NBLK), NTHR, 0, stream>>>(
      points, gt,
      enc_w1, enc_b1, enc_w2, enc_b2, enc_w3, enc_b3,
      att_w1, att_b1, att_w2, att_b2,
      lstm_wih, lstm_whh, lstm_bih, lstm_bhh,
      ref_w1, ref_b1, ref_w2, ref_b2,
      out, ws);
}

// Round 6
// 2893.056 us; speedup vs baseline: 1.1270x; 1.1270x over previous
//
#include <hip/hip_runtime.h>
#include <math.h>

#define BB 4
#define N0 4096
#define NEWP 1152
#define GD 256
#define HD 128
#define KSEL 64
#define NSTEPS 10
#define NMAX (N0 + NSTEPS*NEWP)   /* 15616 */
#define NNEW (NSTEPS*NEWP)        /* 11520 */

#define NBLK 256
#define NTHR 512

/* ---- workspace layout (float offsets) ---- */
#define OFF_CANVAS 0
#define OFF_MINAB  (OFF_CANVAS + BB*NMAX*3)
#define OFF_MINCD  (OFF_MINAB + 2*BB*N0)
#define OFF_GMAX   (OFF_MINCD + BB*NNEW + BB*N0)
#define OFF_H      (OFF_GMAX + BB*GD)
#define OFF_C      (OFF_H + 2*BB*HD)
#define OFF_ACC    (OFF_C + 2*BB*HD)
#define OFF_CENTER (OFF_ACC + 16)
#define OFF_PART   (OFF_CENTER + 32)
#define OFF_GPRE   (OFF_PART + BB*32*8)      /* 4*512 gate partials */

#define AGT __HIP_MEMORY_SCOPE_AGENT

/* coherent (cache-bypassing, IF-coherence-point) accessors for cross-block
   data. Weights/inputs keep normal cached loads. */
__device__ __forceinline__ float cld(const float* p){
  return __hip_atomic_load((float*)p, __ATOMIC_RELAXED, AGT);
}
__device__ __forceinline__ void cst(float* p, float v){
  __hip_atomic_store(p, v, __ATOMIC_RELAXED, AGT);
}
__device__ __forceinline__ unsigned culd(const unsigned* p){
  return __hip_atomic_load((unsigned*)p, __ATOMIC_RELAXED, AGT);
}
__device__ __forceinline__ void cust(unsigned* p, unsigned v){
  __hip_atomic_store(p, v, __ATOMIC_RELAXED, AGT);
}
__device__ __forceinline__ float ldc(const float* p, bool coh){
  return coh ? cld(p) : *p;
}

__device__ __forceinline__ unsigned enc_f(float f){
  unsigned u = __float_as_uint(f);
  return (u & 0x80000000u) ? ~u : (u | 0x80000000u);
}
__device__ __forceinline__ float dec_f(unsigned e){
  unsigned u = (e & 0x80000000u) ? (e & 0x7fffffffu) : ~e;
  return __uint_as_float(u);
}
__device__ __forceinline__ float sigm(float x){ return 1.f/(1.f+expf(-x)); }

__device__ __forceinline__ float block_sum(float v, volatile float* red){
#pragma unroll
  for (int s=32;s>0;s>>=1) v += __shfl_down(v, s, 64);
  int lane = threadIdx.x & 63, w = threadIdx.x >> 6, nw = blockDim.x >> 6;
  __syncthreads();
  if (lane==0) red[w] = v;
  __syncthreads();
  if (w==0){
    float x = (lane < nw) ? red[lane] : 0.f;
#pragma unroll
    for (int s=8;s>0;s>>=1) x += __shfl_down(x, s, 64);
    if (lane==0) red[0] = x;
  }
  __syncthreads();
  float r = red[0];
  __syncthreads();
  return r;
}
__device__ __forceinline__ float block_max(float v, volatile float* red){
#pragma unroll
  for (int s=32;s>0;s>>=1) v = fmaxf(v, __shfl_down(v, s, 64));
  int lane = threadIdx.x & 63, w = threadIdx.x >> 6, nw = blockDim.x >> 6;
  __syncthreads();
  if (lane==0) red[w] = v;
  __syncthreads();
  if (w==0){
    float x = (lane < nw) ? red[lane] : -3.4e38f;
#pragma unroll
    for (int s=8;s>0;s>>=1) x = fmaxf(x, __shfl_down(x, s, 64));
    if (lane==0) red[0] = x;
  }
  __syncthreads();
  float r = red[0];
  __syncthreads();
  return r;
}

/* ---- fence-free grid barrier: 2-level monotonic arrive/spin.
   s_sleep(32) backoff keeps spin fetch low (proven r4). ---- */
__device__ __align__(128) unsigned g_grp[256];   /* 8 counters, stride 32 */
__device__ __align__(128) unsigned g_root;
__device__ __align__(128) unsigned g_gen;

__device__ __forceinline__ void gsync(){
  __syncthreads();
  if (threadIdx.x == 0){
    unsigned snap = __hip_atomic_load(&g_gen, __ATOMIC_RELAXED, AGT);
    asm volatile("" ::: "memory");
    int g = blockIdx.x >> 5;
    unsigned od = __hip_atomic_fetch_add(&g_grp[g*32], 1u, __ATOMIC_RELAXED, AGT);
    bool done = false;
    if ((od & 31u) == 31u){
      unsigned rd = __hip_atomic_fetch_add(&g_root, 1u, __ATOMIC_RELAXED, AGT);
      if ((rd & 7u) == 7u){
        __hip_atomic_fetch_add(&g_gen, 1u, __ATOMIC_RELAXED, AGT);
        done = true;
      }
    }
    if (!done){
      while (__hip_atomic_load(&g_gen, __ATOMIC_RELAXED, AGT) == snap)
        __builtin_amdgcn_s_sleep(32);
    }
    asm volatile("" ::: "memory");
  }
  __syncthreads();
}

/* one 16KB shared-memory arena, aliased per phase */
struct alignas(16) SU {
  union {
    struct { float sy0[1024], sy1[1024], sy2[1024], sny[1024]; } ch;
    struct { float sBatt[128]; float sGH[GD+HD]; float red[16]; } sl;
    struct { float red[16]; float sC[3]; unsigned cbufA[2][8]; unsigned cbufB[2][8];
             int tieCnt; int tieIdx[256]; } sa;
    struct { float sG[512]; float sH[HD]; float sRf[HD]; } re;
    struct { float red[16]; } rd;
  } u;
};

/* fused enc1->enc2->enc3 for one point, 16-dim chunk at d0 (NC=1 only:
   f1[64]+sacc[16]+accd[16] ~= 111 live regs, fits the 128-VGPR budget of
   waves_per_eu(2,2) -- the r5 version of this code ran at a forced 64-VGPR
   allocation and spilled catastrophically).
   enc2 in k-tiles of 16 held in registers: j-outer loop reads
   w2[j][k0..k0+15] (one 64B line, wave-uniform) and FMAs into 16
   INDEPENDENT accumulators (16 indep chains; 1 line per 16 FMA).
   Summation orders (f2: j=0..63, f3: k=0..127) bitwise-match reference. */
__device__ __forceinline__ void enc123_point(
    float p0, float p1, float p2, int d0,
    const float* __restrict__ w1, const float* __restrict__ b1,
    const float* __restrict__ w2, const float* __restrict__ b2,
    const float* __restrict__ w3, const float* __restrict__ b3,
    bool act, unsigned* gmaxrow, int tid)
{
  float f1[64];
#pragma unroll
  for (int j=0;j<64;j++)
    f1[j] = fmaxf(0.f, b1[j] + p0*w1[j] + p1*w1[64+j] + p2*w1[128+j]);
  float accd[16];
#pragma unroll
  for (int c=0;c<16;c++) accd[c] = b3[d0 + c];
#pragma unroll 1
  for (int k0=0;k0<128;k0+=16){
    float sacc[16];
#pragma unroll
    for (int kk=0;kk<16;kk++) sacc[kk] = b2[k0+kk];
#pragma unroll
    for (int j=0;j<64;j++){
      const float* wr = w2 + j*128 + k0;     /* 64B line, wave-uniform */
      float fj = f1[j];
#pragma unroll
      for (int kk=0;kk<16;kk++) sacc[kk] = fmaf(fj, wr[kk], sacc[kk]);
    }
#pragma unroll
    for (int kk=0;kk<16;kk++){
      float fv = fmaxf(sacc[kk], 0.f);
      const float* wr3 = w3 + (size_t)(k0+kk)*256 + d0;  /* 64B line */
#pragma unroll
      for (int c=0;c<16;c++) accd[c] = fmaf(fv, wr3[c], accd[c]);
    }
  }
#pragma unroll
  for (int c=0;c<16;c++){
    float v = act ? accd[c] : -3.4e38f;
#pragma unroll
    for (int s2=32;s2>0;s2>>=1) v = fmaxf(v, __shfl_down(v, s2, 64));
    if ((tid & 63) == 0) atomicMax(&gmaxrow[d0 + c], enc_f(v));
  }
}

/* one chamfer tile; min chain split in two (min is order-independent) */
template<int QN>
__device__ __forceinline__ void chamfer_tile(
    const float* X, const float* Y, unsigned* mp,
    int Nx, int xbase, int tn, bool xcv, bool ycv,
    float* sy0, float* sy1, float* sy2, float* sny, int tid)
{
  for (int tt=tid; tt<tn; tt+=NTHR){
    const float* yp = Y + (size_t)tt*3;
    float y0=ldc(yp,ycv), y1=ldc(yp+1,ycv), y2=ldc(yp+2,ycv);
    sy0[tt]=-2.f*y0; sy1[tt]=-2.f*y1; sy2[tt]=-2.f*y2;
    sny[tt]=y0*y0+y1*y1+y2*y2;
  }
  __syncthreads();
  float X0[QN],X1[QN],X2[QN],NXr[QN],MNa[QN],MNb[QN]; int XI[QN]; bool VA[QN];
#pragma unroll
  for (int q=0;q<QN;q++){
    int x = xbase + q*NTHR + tid;
    VA[q] = x < Nx;
    int xc = VA[q] ? x : 0;
    const float* xp = X + (size_t)xc*3;
    X0[q]=ldc(xp,xcv); X1[q]=ldc(xp+1,xcv); X2[q]=ldc(xp+2,xcv);
    NXr[q] = X0[q]*X0[q] + X1[q]*X1[q] + X2[q]*X2[q];
    MNa[q] = 3.4e38f; MNb[q] = 3.4e38f; XI[q] = xc;
  }
  const float4* v0 = (const float4*)sy0;
  const float4* v1 = (const float4*)sy1;
  const float4* v2 = (const float4*)sy2;
  const float4* vn = (const float4*)sny;
  int j4n = tn >> 2;
  for (int j=0;j<j4n;j++){
    float4 a0 = v0[j], a1 = v1[j], a2 = v2[j], an = vn[j];
#pragma unroll
    for (int e=0;e<4;e++){
      float y0 = ((const float*)&a0)[e];
      float y1 = ((const float*)&a1)[e];
      float y2 = ((const float*)&a2)[e];
      float ny = ((const float*)&an)[e];
#pragma unroll
      for (int q=0;q<QN;q++){
        float d = fmaf(X0[q], y0, fmaf(X1[q], y1, fmaf(X2[q], y2, ny)));
        if (e & 1) MNb[q] = fminf(MNb[q], d);
        else       MNa[q] = fminf(MNa[q], d);
      }
    }
  }
  for (int j=j4n*4; j<tn; j++){
    float y0=sy0[j], y1=sy1[j], y2=sy2[j], ny=sny[j];
#pragma unroll
    for (int q=0;q<QN;q++){
      float d = fmaf(X0[q], y0, fmaf(X1[q], y1, fmaf(X2[q], y2, ny)));
      MNa[q] = fminf(MNa[q], d);
    }
  }
#pragma unroll
  for (int q=0;q<QN;q++)
    if (VA[q]) atomicMin(&mp[XI[q]], enc_f(fminf(MNa[q], MNb[q]) + NXr[q]));
}

__global__ __attribute__((amdgpu_flat_work_group_size(NTHR,NTHR), amdgpu_waves_per_eu(2,2)))
void mega_kernel(
    const float* __restrict__ points, const float* __restrict__ gt,
    const float* __restrict__ w1,  const float* __restrict__ b1,
    const float* __restrict__ w2,  const float* __restrict__ b2,
    const float* __restrict__ w3,  const float* __restrict__ b3,
    const float* __restrict__ aw1, const float* __restrict__ ab1,
    const float* __restrict__ aw2, const float* __restrict__ ab2,
    const float* __restrict__ wih, const float* __restrict__ whh,
    const float* __restrict__ bih, const float* __restrict__ bhh,
    const float* __restrict__ rw1, const float* __restrict__ rb1,
    const float* __restrict__ rw2, const float* __restrict__ rb2,
    float* __restrict__ out, float* __restrict__ ws)
{
  __shared__ SU su;
  const int tid = threadIdx.x;
  const int blk = blockIdx.x;

  float* canvas   = ws + OFF_CANVAS;
  unsigned* minAB = (unsigned*)(ws + OFF_MINAB);
  unsigned* minCD = (unsigned*)(ws + OFF_MINCD);
  unsigned* gmax  = (unsigned*)(ws + OFF_GMAX);
  float* hb       = ws + OFF_H;
  float* cb       = ws + OFF_C;
  float* acc      = ws + OFF_ACC;
  float* centerb  = ws + OFF_CENTER;
  float* partb    = ws + OFF_PART;
  float* gpre     = ws + OFF_GPRE;

  /* ============ P0: init ============ */
  {
    int gid = blk*NTHR + tid;
    if (gid < BB*N0*3){
      int b = gid/(N0*3), r = gid - b*(N0*3);
      cst(&canvas[(size_t)b*NMAX*3 + r], points[gid]);
    }
    if (gid < 2*BB*N0) cust(&minAB[gid], 0xFFFFFFFFu);
    if (gid < BB*NNEW + BB*N0) cust(&minCD[gid], 0xFFFFFFFFu);
    if (gid < BB*GD) cust(&gmax[gid], 0u);
    if (gid < 2*BB*HD){ cst(&hb[gid], 0.f); cst(&cb[gid], 0.f); }
  }
  gsync();

  /* ============ P1: fused enc123 + max-pool of the 16384 initial points.
     256 blocks = 16 ptg-pairs x 16 d-groups; each block does two
     sequential 512-point groups (NC=1 register shape). ============ */
  {
    int ptgg = blk >> 4, dcg = blk & 15;
#pragma unroll 1
    for (int h=0; h<2; h++){
      int gp = (ptgg*2 + h)*NTHR + tid;    /* 0..16383 */
      int b  = gp >> 12;
      const float* p = points + (size_t)gp*3;
      float p0 = p[0], p1 = p[1], p2 = p[2];
      enc123_point(p0, p1, p2, dcg*16, w1, b1, w2, b2, w3, b3,
                   true, &gmax[b*GD], tid);
    }
  }
  gsync();

  /* ============ 10-step loop ============ */
  for (int t=0; t<NSTEPS; t++){
    int N   = N0 + t*NEWP;
    int nch = (N + 511) >> 9;          /* chunks of 512, max 31 */
    float* h_in  = hb + (t&1)*BB*HD;
    float* h_out = hb + ((t+1)&1)*BB*HD;
    float* c_in  = cb + (t&1)*BB*HD;
    float* c_out = cb + ((t+1)&1)*BB*HD;

    /* ---- SL phase: attention partials (blocks 0..4nch-1, <=124)
            + LSTM gate precompute (blocks 252..255) ---- */
    if (blk < 4*nch){
      int b = blk / nch, ch = blk - b*nch;
      if (tid < GD+HD)
        su.u.sl.sGH[tid] = (tid < GD) ? dec_f(culd(&gmax[b*GD + tid]))
                                      : cld(&h_in[b*HD + (tid-GD)]);
      __syncthreads();
      if (tid < 128){
        float a0=0.f,a1=0.f,a2=0.f,a3=0.f;
        for (int k=0;k<GD+HD;k+=4){
          a0 = fmaf(su.u.sl.sGH[k  ], aw1[(3+k  )*128 + tid], a0);
          a1 = fmaf(su.u.sl.sGH[k+1], aw1[(4+k  )*128 + tid], a1);
          a2 = fmaf(su.u.sl.sGH[k+2], aw1[(5+k  )*128 + tid], a2);
          a3 = fmaf(su.u.sl.sGH[k+3], aw1[(6+k  )*128 + tid], a3);
        }
        su.u.sl.sBatt[tid] = ab1[tid] + ((a0+a1)+(a2+a3));
      }
      __syncthreads();
      int i = ch*NTHR + tid;
      bool act = i < N;
      float p0=0.f,p1=0.f,p2=0.f,s=-3.4e38f;
      if (act){
        const float* pp = canvas + (size_t)(b*NMAX + i)*3;
        p0=cld(pp); p1=cld(pp+1); p2=cld(pp+2);
        float s0=0.f,s1=0.f,s2=0.f,s3=0.f;
        for (int j=0;j<128;j+=4){
          float v0 = su.u.sl.sBatt[j  ] + p0*aw1[j  ] + p1*aw1[128+j  ] + p2*aw1[256+j  ];
          float v1 = su.u.sl.sBatt[j+1] + p0*aw1[j+1] + p1*aw1[128+j+1] + p2*aw1[256+j+1];
          float v2 = su.u.sl.sBatt[j+2] + p0*aw1[j+2] + p1*aw1[128+j+2] + p2*aw1[256+j+2];
          float v3 = su.u.sl.sBatt[j+3] + p0*aw1[j+3] + p1*aw1[128+j+3] + p2*aw1[256+j+3];
          s0 = fmaf(fmaxf(v0,0.f), aw2[j  ], s0);
          s1 = fmaf(fmaxf(v1,0.f), aw2[j+1], s1);
          s2 = fmaf(fmaxf(v2,0.f), aw2[j+2], s2);
          s3 = fmaf(fmaxf(v3,0.f), aw2[j+3], s3);
        }
        s = ab2[0] + ((s0+s1)+(s2+s3));
      }
      float mb = block_max(s, su.u.sl.red);
      float e = act ? expf(s - mb) : 0.f;
      float se = block_sum(e, su.u.sl.red);
      float wx = block_sum(e*p0, su.u.sl.red);
      float wy = block_sum(e*p1, su.u.sl.red);
      float wz = block_sum(e*p2, su.u.sl.red);
      if (tid==0){
        float* pr = partb + (size_t)(b*32 + ch)*8;
        cst(pr+0, mb); cst(pr+1, se); cst(pr+2, wx); cst(pr+3, wy); cst(pr+4, wz);
      }
    } else if (blk >= 252){
      int b = blk - 252;
      if (tid < GD+HD)
        su.u.sl.sGH[tid] = (tid < GD) ? dec_f(culd(&gmax[b*GD + tid]))
                                      : cld(&h_in[b*HD + (tid-GD)]);
      __syncthreads();
      {
        int o = tid;
        float g0=0.f,g1=0.f,g2=0.f,g3=0.f;
        for (int k=0;k<GD;k+=4){
          g0 = fmaf(su.u.sl.sGH[k  ], wih[(size_t)(k  )*512 + o], g0);
          g1 = fmaf(su.u.sl.sGH[k+1], wih[(size_t)(k+1)*512 + o], g1);
          g2 = fmaf(su.u.sl.sGH[k+2], wih[(size_t)(k+2)*512 + o], g2);
          g3 = fmaf(su.u.sl.sGH[k+3], wih[(size_t)(k+3)*512 + o], g3);
        }
        for (int k=0;k<HD;k+=4){
          g0 = fmaf(su.u.sl.sGH[GD+k  ], whh[(size_t)(k  )*512 + o], g0);
          g1 = fmaf(su.u.sl.sGH[GD+k+1], whh[(size_t)(k+1)*512 + o], g1);
          g2 = fmaf(su.u.sl.sGH[GD+k+2], whh[(size_t)(k+2)*512 + o], g2);
          g3 = fmaf(su.u.sl.sGH[GD+k+3], whh[(size_t)(k+3)*512 + o], g3);
        }
        cst(&gpre[b*512 + o], bih[o] + bhh[o] + ((g0+g1)+(g2+g3)));
      }
    }
    gsync();

    /* ---- stepA phase: center+top-K (blocks 0..3, 512 thr)
            + incremental chamfer in otherwise-idle blocks ---- */
    if (blk < 4){
      int b = blk;
      const float* cv = canvas + (size_t)b*NMAX*3;
      int lane = tid & 63, wid = tid >> 6;

      float pm=-3.4e38f, pse=0.f, pwx=0.f, pwy=0.f, pwz=0.f;
      if (tid < nch){
        const float* pp = partb + (size_t)(b*32 + tid)*8;
        pm=cld(pp); pse=cld(pp+1); pwx=cld(pp+2); pwy=cld(pp+3); pwz=cld(pp+4);
      }
      float M = block_max(pm, su.u.sa.red);
      float w = (tid < nch) ? expf(pm - M) : 0.f;
      float se = block_sum(pse*w, su.u.sa.red);
      float wx = block_sum(pwx*w, su.u.sa.red);
      float wy = block_sum(pwy*w, su.u.sa.red);
      float wz = block_sum(pwz*w, su.u.sa.red);
      if (tid==0){ su.u.sa.sC[0]=wx/se; su.u.sa.sC[1]=wy/se; su.u.sa.sC[2]=wz/se; }
      __syncthreads();
      float cx=su.u.sa.sC[0], cy=su.u.sa.sC[1], cz=su.u.sa.sC[2];
      if (tid<3) cst(&centerb[b*3+tid], su.u.sa.sC[tid]);

      unsigned ur[32];
#pragma unroll
      for (int q=0;q<32;q+=8){
        float px[8], py[8], pz[8];
#pragma unroll
        for (int r=0;r<8;r++){
          int i = tid + (q+r)*NTHR;
          int ic2 = (i < N) ? i : 0;
          const float* p = cv + (size_t)ic2*3;
          px[r]=cld(p); py[r]=cld(p+1); pz[r]=cld(p+2);
        }
#pragma unroll
        for (int r=0;r<8;r++){
          int i = tid + (q+r)*NTHR;
          ur[q+r] = 0xFFFFFFFFu;
          if (i < N){
            float dx=px[r]-cx, dy=py[r]-cy, dz=pz[r]-cz;
            ur[q+r] = __float_as_uint(dx*dx + dy*dy + dz*dz);
          }
        }
      }

      unsigned T = 0u;
      int cntBelow = 0;
      int par = 0;
      {
        unsigned cand = 1u<<30;
        unsigned tc = 0;
#pragma unroll
        for (int q=0;q<32;q++) tc += (ur[q] < cand) ? 1u : 0u;
#pragma unroll
        for (int s2=32;s2>0;s2>>=1) tc += __shfl_down(tc, s2, 64);
        if (lane==0) su.u.sa.cbufA[par][wid] = tc;
        __syncthreads();
        unsigned tot = 0;
#pragma unroll
        for (int i2=0;i2<8;i2++) tot += su.u.sa.cbufA[par][i2];
        if ((int)tot < KSEL){ T = cand; cntBelow = (int)tot; }
        par ^= 1;
      }
      for (int bit=29; bit>=1; bit-=2){
        unsigned q1 = 1u<<(bit-1);
        unsigned c1 = T + q1, c2 = T + 2u*q1, c3 = T + 3u*q1;
        unsigned ta = 0, tb = 0;
#pragma unroll
        for (int q=0;q<32;q++){
          unsigned u = ur[q];
          ta += (u < c1 ? 1u : 0u) | (u < c2 ? 0x10000u : 0u);
          tb += (u < c3 ? 1u : 0u);
        }
#pragma unroll
        for (int s2=32;s2>0;s2>>=1){ ta += __shfl_down(ta, s2, 64); tb += __shfl_down(tb, s2, 64); }
        if (lane==0){ su.u.sa.cbufA[par][wid] = ta; su.u.sa.cbufB[par][wid] = tb; }
        __syncthreads();
        unsigned sa2 = 0, sb2 = 0;
#pragma unroll
        for (int i2=0;i2<8;i2++){ sa2 += su.u.sa.cbufA[par][i2]; sb2 += su.u.sa.cbufB[par][i2]; }
        int n1 = (int)(sa2 & 0xFFFFu), n2 = (int)(sa2 >> 16), n3 = (int)sb2;
        if (n3 < KSEL){ T = c3; cntBelow = n3; }
        else if (n2 < KSEL){ T = c2; cntBelow = n2; }
        else if (n1 < KSEL){ T = c1; cntBelow = n1; }
        par ^= 1;
      }
      int kneed = KSEL - cntBelow;

      if (tid==0) su.u.sa.tieCnt = 0;
      __syncthreads();
      float sx=0.f, sy=0.f, sz=0.f;
#pragma unroll
      for (int q=0;q<32;q++){
        unsigned uu = ur[q];
        if (uu < T){
          const float* p = cv + (size_t)(tid + q*NTHR)*3;
          sx += cld(p); sy += cld(p+1); sz += cld(p+2);
        } else if (uu == T){
          int pos = atomicAdd(&su.u.sa.tieCnt, 1);
          if (pos < 256) su.u.sa.tieIdx[pos] = tid + q*NTHR;
        }
      }
      __syncthreads();
      sx = block_sum(sx, su.u.sa.red);
      sy = block_sum(sy, su.u.sa.red);
      sz = block_sum(sz, su.u.sa.red);
      if (tid==0){
        int mm = su.u.sa.tieCnt < 256 ? su.u.sa.tieCnt : 256;
        for (int tt=0; tt<kneed; tt++){
          int best=-1, bi=0x7fffffff;
          for (int q=0;q<mm;q++){ int v = su.u.sa.tieIdx[q]; if (v < bi){ bi=v; best=q; } }
          if (best >= 0){
            su.u.sa.tieIdx[best] = 0x7fffffff;
            const float* p = cv + (size_t)bi*3;
            sx += cld(p); sy += cld(p+1); sz += cld(p+2);
          }
        }
        cst(&centerb[16 + b*3 + 0], sx/KSEL - cx);
        cst(&centerb[16 + b*3 + 1], sy/KSEL - cy);
        cst(&centerb[16 + b*3 + 2], sz/KSEL - cz);
      }
    } else if (t == 0 && blk < 68){
      /* dir0: canvas[0..N0) -> gt. 64 blocks. */
      int rem = blk - 4;
      int b = rem >> 4, l = rem & 15, xb = l >> 2, yb = l & 3;
      chamfer_tile<2>(canvas + (size_t)b*NMAX*3, gt + ((size_t)b*N0 + yb*1024)*3,
                      minAB + b*N0, N0, xb*1024, 1024, true, false,
                      su.u.ch.sy0, su.u.ch.sy1, su.u.ch.sy2, su.u.ch.sny, tid);
    } else if (t >= 1 && blk < 20){
      /* dir2 incremental: new points of step t-1 -> gt. 16 blocks. */
      int rem = blk - 4;
      int b = rem >> 2, yb = rem & 3;
      chamfer_tile<3>(canvas + ((size_t)b*NMAX + N0 + (size_t)(t-1)*NEWP)*3,
                      gt + ((size_t)b*N0 + yb*1024)*3,
                      minCD + b*NNEW + (t-1)*NEWP, NEWP, 0, 1024, true, false,
                      su.u.ch.sy0, su.u.ch.sy1, su.u.ch.sy2, su.u.ch.sny, tid);
    }
    gsync();

    /* ---- REF phase: LSTM finish + refine-decode + canvas append
            + fused enc123 of the new points (blocks 0..191) ---- */
    if (blk < 192){
      int bx = blk >> 6, b = (blk >> 4) & 3, dcg = blk & 15;  /* 3*4*16 */
      float cx = cld(&centerb[b*3+0]), cy = cld(&centerb[b*3+1]), cz = cld(&centerb[b*3+2]);
      float fx = cld(&centerb[16+b*3+0]), fy = cld(&centerb[16+b*3+1]), fz = cld(&centerb[16+b*3+2]);
      {
        int o = tid;
        float gg = cld(&gpre[b*512 + o]);
        gg += cx*wih[(size_t)256*512+o] + cy*wih[(size_t)257*512+o] + cz*wih[(size_t)258*512+o];
        gg += fx*wih[(size_t)259*512+o] + fy*wih[(size_t)260*512+o] + fz*wih[(size_t)261*512+o];
        su.u.re.sG[o] = gg;
      }
      __syncthreads();
      if (tid < HD){
        float gi=su.u.re.sG[tid], gf=su.u.re.sG[128+tid], gg2=su.u.re.sG[256+tid], go=su.u.re.sG[384+tid];
        float cn = sigm(gf)*cld(&c_in[b*HD+tid]) + sigm(gi)*tanhf(gg2);
        float hn = sigm(go)*tanhf(cn);
        su.u.re.sH[tid] = hn;
        if (bx==0 && dcg==0){ cst(&c_out[b*HD+tid], cn); cst(&h_out[b*HD+tid], hn); }
      }
      __syncthreads();
      if (tid < HD){
        float a0=0.f,a1=0.f,a2=0.f,a3=0.f;
        for (int k=0;k<HD;k+=4){
          a0 = fmaf(su.u.re.sH[k  ], rw1[(k  )*HD + tid], a0);
          a1 = fmaf(su.u.re.sH[k+1], rw1[(k+1)*HD + tid], a1);
          a2 = fmaf(su.u.re.sH[k+2], rw1[(k+2)*HD + tid], a2);
          a3 = fmaf(su.u.re.sH[k+3], rw1[(k+3)*HD + tid], a3);
        }
        su.u.re.sRf[tid] = fmaxf(rb1[tid] + ((a0+a1)+(a2+a3)), 0.f);
      }
      __syncthreads();
      int i = bx*NTHR + tid;
      bool act = i < NEWP;
      int ic = act ? i : 0;
      float a0 = rb2[3*ic], a1 = rb2[3*ic+1], a2 = rb2[3*ic+2];
      for (int k=0;k<HD;k++){
        const float* wv = rw2 + (size_t)k*(NEWP*3) + 3*ic;
        float hk = su.u.re.sRf[k];
        a0 = fmaf(hk, wv[0], a0); a1 = fmaf(hk, wv[1], a1); a2 = fmaf(hk, wv[2], a2);
      }
      float p0 = fmaf(a0, 0.02f, cx), p1 = fmaf(a1, 0.02f, cy), p2 = fmaf(a2, 0.02f, cz);
      if (act && dcg==0){
        float* cp = canvas + ((size_t)b*NMAX + N + i)*3;
        cst(cp+0, p0); cst(cp+1, p1); cst(cp+2, p2);
      }
      if (t < NSTEPS-1){
        enc123_point(p0, p1, p2, dcg*16, w1, b1, w2, b2, w3, b3,
                     act, &gmax[b*GD], tid);
      }
    }
    gsync();
  }

  /* ============ final chamfer: dir1 (128), dir3 (96), dir2-last (16) ==== */
  {
    if (blk < 128){
      int b = blk >> 5, l = blk & 31, xb = l >> 4, yb = l & 15;
      int tn = min(1024, NMAX - yb*1024);
      chamfer_tile<4>(gt + (size_t)b*N0*3, canvas + ((size_t)b*NMAX + yb*1024)*3,
                      minAB + BB*N0 + b*N0, N0, xb*2048, tn, false, true,
                      su.u.ch.sy0, su.u.ch.sy1, su.u.ch.sy2, su.u.ch.sny, tid);
    } else if (blk < 224){
      int rem = blk - 128;
      int b = rem/24, l = rem%24, xb = l/12, yb = l%12;
      int tn = min(1024, NNEW - yb*1024);
      chamfer_tile<4>(gt + (size_t)b*N0*3, canvas + ((size_t)b*NMAX + N0 + yb*1024)*3,
                      minCD + BB*NNEW + b*N0, N0, xb*2048, tn, false, true,
                      su.u.ch.sy0, su.u.ch.sy1, su.u.ch.sy2, su.u.ch.sny, tid);
    } else if (blk < 240){
      int rem = blk - 224;
      int b = rem >> 2, yb = rem & 3;
      chamfer_tile<3>(canvas + ((size_t)b*NMAX + N0 + (size_t)(NSTEPS-1)*NEWP)*3,
                      gt + ((size_t)b*N0 + yb*1024)*3,
                      minCD + b*NNEW + (NSTEPS-1)*NEWP, NEWP, 0, 1024, true, false,
                      su.u.ch.sy0, su.u.ch.sy1, su.u.ch.sy2, su.u.ch.sny, tid);
    }
  }
  gsync();

  /* ============ reduce (blocks 0..15) ============ */
  if (blk < 16){
    int s = blk, dir = s>>2, b = s&3;
    const unsigned* mp; int len;
    if (dir==0){      mp=minAB + b*N0;            len=N0; }
    else if (dir==1){ mp=minAB + BB*N0 + b*N0;    len=N0; }
    else if (dir==2){ mp=minCD + b*NNEW;          len=NNEW; }
    else {            mp=minCD + BB*NNEW + b*N0;  len=N0; }
    float v = 0.f;
    int i = tid;
    for (; i + 3*NTHR < len; i += 4*NTHR){
      unsigned u0=culd(mp+i), u1=culd(mp+i+NTHR), u2=culd(mp+i+2*NTHR), u3=culd(mp+i+3*NTHR);
      v += dec_f(u0); v += dec_f(u1); v += dec_f(u2); v += dec_f(u3);
    }
    for (; i < len; i += NTHR) v += dec_f(culd(mp+i));
    v = block_sum(v, su.u.rd.red);
    if (tid==0) cst(&acc[s], v);
  }
  gsync();

  /* ============ finish ============ */
  if (blk == 0 && tid == 0){
    float cd1 = 0.f, cd2 = 0.f;
    for (int b=0;b<BB;b++) cd1 += cld(&acc[b])/(float)N0 + cld(&acc[4+b])/(float)N0;
    for (int b=0;b<BB;b++) cd2 += cld(&acc[8+b])/(float)NNEW + cld(&acc[12+b])/(float)N0;
    out[0] = 0.1f*(cd1/BB) + 1.0f*(cd2/BB);
  }
}

extern "C" void kernel_launch(void* const* d_in, const int* in_sizes, int n_in,
                              void* d_out, int out_size, void* d_ws, size_t ws_size,
                              hipStream_t stream) {
  (void)in_sizes; (void)n_in; (void)out_size; (void)ws_size;
  const float* points   = (const float*)d_in[0];
  const float* gt       = (const float*)d_in[1];
  const float* enc_w1   = (const float*)d_in[2];
  const float* enc_b1   = (const float*)d_in[3];
  const float* enc_w2   = (const float*)d_in[4];
  const float* enc_b2   = (const float*)d_in[5];
  const float* enc_w3   = (const float*)d_in[6];
  const float* enc_b3   = (const float*)d_in[7];
  const float* att_w1   = (const float*)d_in[8];
  const float* att_b1   = (const float*)d_in[9];
  const float* att_w2   = (const float*)d_in[10];
  const float* att_b2   = (const float*)d_in[11];
  const float* lstm_wih = (const float*)d_in[12];
  const float* lstm_whh = (const float*)d_in[13];
  const float* lstm_bih = (const float*)d_in[14];
  const float* lstm_bhh = (const float*)d_in[15];
  const float* ref_w1   = (const float*)d_in[16];
  const float* ref_b1   = (const float*)d_in[17];
  const float* ref_w2   = (const float*)d_in[18];
  const float* ref_b2   = (const float*)d_in[19];
  float* out = (float*)d_out;
  float* ws  = (float*)d_ws;

  mega_kernel<<<dim3(NBLK), NTHR, 0, stream>>>(
      points, gt,
      enc_w1, enc_b1, enc_w2, enc_b2, enc_w3, enc_b3,
      att_w1, att_b1, att_w2, att_b2,
      lstm_wih, lstm_whh, lstm_bih, lstm_bhh,
      ref_w1, ref_b1, ref_w2, ref_b2,
      out, ws);
}

// Round 7
// 2565.788 us; speedup vs baseline: 1.2708x; 1.1276x over previous
//
#include <hip/hip_runtime.h>
#include <math.h>

#define BB 4
#define N0 4096
#define NEWP 1152
#define GD 256
#define HD 128
#define KSEL 64
#define NSTEPS 10
#define NMAX (N0 + NSTEPS*NEWP)   /* 15616 */
#define NNEW (NSTEPS*NEWP)        /* 11520 */

#define NBLK 256
#define NTHR 512

/* ---- workspace layout (float offsets) ---- */
#define OFF_CANVAS 0
#define OFF_MINAB  (OFF_CANVAS + BB*NMAX*3)
#define OFF_MINCD  (OFF_MINAB + 2*BB*N0)
#define OFF_GMAX   (OFF_MINCD + BB*NNEW + BB*N0)
#define OFF_H      (OFF_GMAX + BB*GD)
#define OFF_C      (OFF_H + 2*BB*HD)
#define OFF_ACC    (OFF_C + 2*BB*HD)
#define OFF_CENTER (OFF_ACC + 16)
#define OFF_PART   (OFF_CENTER + 32)
#define OFF_GPRE   (OFF_PART + BB*32*8)      /* 4*512 gate partials */

#define AGT __HIP_MEMORY_SCOPE_AGENT

/* coherent (cache-bypassing, IF-coherence-point) accessors for cross-block
   data. Weights/inputs keep normal cached loads. */
__device__ __forceinline__ float cld(const float* p){
  return __hip_atomic_load((float*)p, __ATOMIC_RELAXED, AGT);
}
__device__ __forceinline__ void cst(float* p, float v){
  __hip_atomic_store(p, v, __ATOMIC_RELAXED, AGT);
}
__device__ __forceinline__ unsigned culd(const unsigned* p){
  return __hip_atomic_load((unsigned*)p, __ATOMIC_RELAXED, AGT);
}
__device__ __forceinline__ void cust(unsigned* p, unsigned v){
  __hip_atomic_store(p, v, __ATOMIC_RELAXED, AGT);
}
__device__ __forceinline__ float ldc(const float* p, bool coh){
  return coh ? cld(p) : *p;
}

__device__ __forceinline__ unsigned enc_f(float f){
  unsigned u = __float_as_uint(f);
  return (u & 0x80000000u) ? ~u : (u | 0x80000000u);
}
__device__ __forceinline__ float dec_f(unsigned e){
  unsigned u = (e & 0x80000000u) ? (e & 0x7fffffffu) : ~e;
  return __uint_as_float(u);
}
__device__ __forceinline__ float sigm(float x){ return 1.f/(1.f+expf(-x)); }

__device__ __forceinline__ float block_sum(float v, volatile float* red){
#pragma unroll
  for (int s=32;s>0;s>>=1) v += __shfl_down(v, s, 64);
  int lane = threadIdx.x & 63, w = threadIdx.x >> 6, nw = blockDim.x >> 6;
  __syncthreads();
  if (lane==0) red[w] = v;
  __syncthreads();
  if (w==0){
    float x = (lane < nw) ? red[lane] : 0.f;
#pragma unroll
    for (int s=8;s>0;s>>=1) x += __shfl_down(x, s, 64);
    if (lane==0) red[0] = x;
  }
  __syncthreads();
  float r = red[0];
  __syncthreads();
  return r;
}
__device__ __forceinline__ float block_max(float v, volatile float* red){
#pragma unroll
  for (int s=32;s>0;s>>=1) v = fmaxf(v, __shfl_down(v, s, 64));
  int lane = threadIdx.x & 63, w = threadIdx.x >> 6, nw = blockDim.x >> 6;
  __syncthreads();
  if (lane==0) red[w] = v;
  __syncthreads();
  if (w==0){
    float x = (lane < nw) ? red[lane] : -3.4e38f;
#pragma unroll
    for (int s=8;s>0;s>>=1) x = fmaxf(x, __shfl_down(x, s, 64));
    if (lane==0) red[0] = x;
  }
  __syncthreads();
  float r = red[0];
  __syncthreads();
  return r;
}

/* ---- fence-free grid barrier: 2-level monotonic arrive/spin.
   s_sleep(32) backoff keeps spin fetch low (proven r4). ---- */
__device__ __align__(128) unsigned g_grp[256];   /* 8 counters, stride 32 */
__device__ __align__(128) unsigned g_root;
__device__ __align__(128) unsigned g_gen;

__device__ __forceinline__ void gsync(){
  __syncthreads();
  if (threadIdx.x == 0){
    unsigned snap = __hip_atomic_load(&g_gen, __ATOMIC_RELAXED, AGT);
    asm volatile("" ::: "memory");
    int g = blockIdx.x >> 5;
    unsigned od = __hip_atomic_fetch_add(&g_grp[g*32], 1u, __ATOMIC_RELAXED, AGT);
    bool done = false;
    if ((od & 31u) == 31u){
      unsigned rd = __hip_atomic_fetch_add(&g_root, 1u, __ATOMIC_RELAXED, AGT);
      if ((rd & 7u) == 7u){
        __hip_atomic_fetch_add(&g_gen, 1u, __ATOMIC_RELAXED, AGT);
        done = true;
      }
    }
    if (!done){
      while (__hip_atomic_load(&g_gen, __ATOMIC_RELAXED, AGT) == snap)
        __builtin_amdgcn_s_sleep(32);
    }
    asm volatile("" ::: "memory");
  }
  __syncthreads();
}

/* one 16KB shared-memory arena, aliased per phase */
struct alignas(16) SU {
  union {
    struct { float sy0[1024], sy1[1024], sy2[1024], sny[1024]; } ch;
    struct { float sBatt[128]; float sGH[GD+HD]; float red[16]; } sl;
    struct { float red[16]; float sC[3]; unsigned cbufA[2][8]; unsigned cbufB[2][8];
             int tieCnt; int tieIdx[256]; } sa;
    struct { float sG[512]; float sH[HD]; float sRf[HD]; } re;
    struct { float red[16]; } rd;
  } u;
};

#define F2PAD 132   /* 64x132 f2 slab in LDS: 16B-aligned rows, bank-spread */

/* LDS-cooperative enc slab: block computes enc1->enc2->enc3 + max-pool for
   64 points with NO d-redundancy (r6's 16x enc2 recompute eliminated).
   Phase A: thread (p=tid&63, kc=tid>>6): f1[64] in regs (8x redundant, cheap),
     16-wide f2 chunk via 16 independent j-chains (w2 lines wave-uniform ->
     scalar loads), relu -> f2l[p][kc*16..+16].
   Phase B: thread (d0=4*(tid&63), pg=tid>>6): acc[8][4]; k-loop in steps of 4:
     4 coalesced float4 w3 rows + 8 broadcast ds_read_b128 of f2 -> 128 FMA.
     16 FMA per LDS read; live set ~60 regs.
   Summation orders bitwise-match reference: f2 j=0..63 per k; f3 k=0..127
   ascending from b3. Max-pool via atomicMax (order-independent). */
__device__ __forceinline__ void enc_slab(
    const float* __restrict__ pts, bool coh,
    const float* __restrict__ w1, const float* __restrict__ b1,
    const float* __restrict__ w2, const float* __restrict__ b2,
    const float* __restrict__ w3, const float* __restrict__ b3,
    unsigned* __restrict__ gmaxrow, float* __restrict__ f2l, int tid)
{
  {
    int p = tid & 63, kc = tid >> 6, k0 = kc*16;
    const float* pp = pts + (size_t)p*3;
    float p0 = ldc(pp,coh), p1 = ldc(pp+1,coh), p2 = ldc(pp+2,coh);
    float f1[64];
#pragma unroll
    for (int j=0;j<64;j++)
      f1[j] = fmaxf(0.f, b1[j] + p0*w1[j] + p1*w1[64+j] + p2*w1[128+j]);
    float sacc[16];
#pragma unroll
    for (int kk=0;kk<16;kk++) sacc[kk] = b2[k0+kk];
#pragma unroll 4
    for (int j=0;j<64;j++){
      const float* wr = w2 + j*128 + k0;   /* wave-uniform -> scalar loads */
      float fj = f1[j];
#pragma unroll
      for (int kk=0;kk<16;kk++) sacc[kk] = fmaf(fj, wr[kk], sacc[kk]);
    }
#pragma unroll
    for (int kk=0;kk<16;kk++) f2l[p*F2PAD + k0 + kk] = fmaxf(sacc[kk], 0.f);
  }
  __syncthreads();
  {
    int dq = tid & 63, pg = tid >> 6;
    int d0 = dq*4;
    float acc[8][4];
#pragma unroll
    for (int q=0;q<8;q++)
#pragma unroll
      for (int j=0;j<4;j++) acc[q][j] = b3[d0+j];
#pragma unroll 1
    for (int ks=0;ks<32;ks++){
      int k = ks*4;
      float4 wv0 = *(const float4*)&w3[(size_t)(k+0)*256 + d0];
      float4 wv1 = *(const float4*)&w3[(size_t)(k+1)*256 + d0];
      float4 wv2 = *(const float4*)&w3[(size_t)(k+2)*256 + d0];
      float4 wv3 = *(const float4*)&w3[(size_t)(k+3)*256 + d0];
      const float* w0p = (const float*)&wv0;
      const float* w1p = (const float*)&wv1;
      const float* w2p = (const float*)&wv2;
      const float* w3p = (const float*)&wv3;
#pragma unroll
      for (int q=0;q<8;q++){
        float4 f = *(const float4*)&f2l[(pg*8+q)*F2PAD + k];  /* broadcast */
#pragma unroll
        for (int j=0;j<4;j++){
          float a = acc[q][j];
          a = fmaf(f.x, w0p[j], a);
          a = fmaf(f.y, w1p[j], a);
          a = fmaf(f.z, w2p[j], a);
          a = fmaf(f.w, w3p[j], a);
          acc[q][j] = a;
        }
      }
    }
#pragma unroll
    for (int j=0;j<4;j++){
      float m = acc[0][j];
#pragma unroll
      for (int q=1;q<8;q++) m = fmaxf(m, acc[q][j]);
      atomicMax(&gmaxrow[d0+j], enc_f(m));
    }
  }
}

/* one chamfer tile; min chain split in two (min is order-independent) */
template<int QN>
__device__ __forceinline__ void chamfer_tile(
    const float* X, const float* Y, unsigned* mp,
    int Nx, int xbase, int tn, bool xcv, bool ycv,
    float* sy0, float* sy1, float* sy2, float* sny, int tid)
{
  for (int tt=tid; tt<tn; tt+=NTHR){
    const float* yp = Y + (size_t)tt*3;
    float y0=ldc(yp,ycv), y1=ldc(yp+1,ycv), y2=ldc(yp+2,ycv);
    sy0[tt]=-2.f*y0; sy1[tt]=-2.f*y1; sy2[tt]=-2.f*y2;
    sny[tt]=y0*y0+y1*y1+y2*y2;
  }
  __syncthreads();
  float X0[QN],X1[QN],X2[QN],NXr[QN],MNa[QN],MNb[QN]; int XI[QN]; bool VA[QN];
#pragma unroll
  for (int q=0;q<QN;q++){
    int x = xbase + q*NTHR + tid;
    VA[q] = x < Nx;
    int xc = VA[q] ? x : 0;
    const float* xp = X + (size_t)xc*3;
    X0[q]=ldc(xp,xcv); X1[q]=ldc(xp+1,xcv); X2[q]=ldc(xp+2,xcv);
    NXr[q] = X0[q]*X0[q] + X1[q]*X1[q] + X2[q]*X2[q];
    MNa[q] = 3.4e38f; MNb[q] = 3.4e38f; XI[q] = xc;
  }
  const float4* v0 = (const float4*)sy0;
  const float4* v1 = (const float4*)sy1;
  const float4* v2 = (const float4*)sy2;
  const float4* vn = (const float4*)sny;
  int j4n = tn >> 2;
  for (int j=0;j<j4n;j++){
    float4 a0 = v0[j], a1 = v1[j], a2 = v2[j], an = vn[j];
#pragma unroll
    for (int e=0;e<4;e++){
      float y0 = ((const float*)&a0)[e];
      float y1 = ((const float*)&a1)[e];
      float y2 = ((const float*)&a2)[e];
      float ny = ((const float*)&an)[e];
#pragma unroll
      for (int q=0;q<QN;q++){
        float d = fmaf(X0[q], y0, fmaf(X1[q], y1, fmaf(X2[q], y2, ny)));
        if (e & 1) MNb[q] = fminf(MNb[q], d);
        else       MNa[q] = fminf(MNa[q], d);
      }
    }
  }
  for (int j=j4n*4; j<tn; j++){
    float y0=sy0[j], y1=sy1[j], y2=sy2[j], ny=sny[j];
#pragma unroll
    for (int q=0;q<QN;q++){
      float d = fmaf(X0[q], y0, fmaf(X1[q], y1, fmaf(X2[q], y2, ny)));
      MNa[q] = fminf(MNa[q], d);
    }
  }
#pragma unroll
  for (int q=0;q<QN;q++)
    if (VA[q]) atomicMin(&mp[XI[q]], enc_f(fminf(MNa[q], MNb[q]) + NXr[q]));
}

__global__ __attribute__((amdgpu_flat_work_group_size(NTHR,NTHR), amdgpu_waves_per_eu(2,2)))
void mega_kernel(
    const float* __restrict__ points, const float* __restrict__ gt,
    const float* __restrict__ w1,  const float* __restrict__ b1,
    const float* __restrict__ w2,  const float* __restrict__ b2,
    const float* __restrict__ w3,  const float* __restrict__ b3,
    const float* __restrict__ aw1, const float* __restrict__ ab1,
    const float* __restrict__ aw2, const float* __restrict__ ab2,
    const float* __restrict__ wih, const float* __restrict__ whh,
    const float* __restrict__ bih, const float* __restrict__ bhh,
    const float* __restrict__ rw1, const float* __restrict__ rb1,
    const float* __restrict__ rw2, const float* __restrict__ rb2,
    float* __restrict__ out, float* __restrict__ ws)
{
  __shared__ SU su;
  __shared__ float f2l[64*F2PAD];     /* 33 KB enc slab */
  const int tid = threadIdx.x;
  const int blk = blockIdx.x;

  float* canvas   = ws + OFF_CANVAS;
  unsigned* minAB = (unsigned*)(ws + OFF_MINAB);
  unsigned* minCD = (unsigned*)(ws + OFF_MINCD);
  unsigned* gmax  = (unsigned*)(ws + OFF_GMAX);
  float* hb       = ws + OFF_H;
  float* cb       = ws + OFF_C;
  float* acc      = ws + OFF_ACC;
  float* centerb  = ws + OFF_CENTER;
  float* partb    = ws + OFF_PART;
  float* gpre     = ws + OFF_GPRE;

  /* ============ P0: init ============ */
  {
    int gid = blk*NTHR + tid;
    if (gid < BB*N0*3){
      int b = gid/(N0*3), r = gid - b*(N0*3);
      cst(&canvas[(size_t)b*NMAX*3 + r], points[gid]);
    }
    if (gid < 2*BB*N0) cust(&minAB[gid], 0xFFFFFFFFu);
    if (gid < BB*NNEW + BB*N0) cust(&minCD[gid], 0xFFFFFFFFu);
    if (gid < BB*GD) cust(&gmax[gid], 0u);
    if (gid < 2*BB*HD){ cst(&hb[gid], 0.f); cst(&cb[gid], 0.f); }
  }
  gsync();

  /* ============ P1: enc slabs of the 16384 initial points.
     256 blocks = 4 b x 64 slabs of 64 points. No redundancy. ============ */
  {
    int b = blk >> 6, slab = blk & 63;
    enc_slab(points + (size_t)(b*N0 + slab*64)*3, false,
             w1, b1, w2, b2, w3, b3, &gmax[b*GD], f2l, tid);
  }
  gsync();

  /* ============ 10-step loop ============ */
  for (int t=0; t<NSTEPS; t++){
    int N   = N0 + t*NEWP;
    int nch = (N + 511) >> 9;          /* chunks of 512, max 29 */
    float* h_in  = hb + (t&1)*BB*HD;
    float* h_out = hb + ((t+1)&1)*BB*HD;
    float* c_in  = cb + (t&1)*BB*HD;
    float* c_out = cb + ((t+1)&1)*BB*HD;

    /* ---- SL phase: attention partials (blocks 0..4nch-1, <=116)
            + LSTM gate precompute (blocks 252..255) ---- */
    if (blk < 4*nch){
      int b = blk / nch, ch = blk - b*nch;
      if (tid < GD+HD)
        su.u.sl.sGH[tid] = (tid < GD) ? dec_f(culd(&gmax[b*GD + tid]))
                                      : cld(&h_in[b*HD + (tid-GD)]);
      __syncthreads();
      if (tid < 128){
        float a0=0.f,a1=0.f,a2=0.f,a3=0.f;
        for (int k=0;k<GD+HD;k+=4){
          a0 = fmaf(su.u.sl.sGH[k  ], aw1[(3+k  )*128 + tid], a0);
          a1 = fmaf(su.u.sl.sGH[k+1], aw1[(4+k  )*128 + tid], a1);
          a2 = fmaf(su.u.sl.sGH[k+2], aw1[(5+k  )*128 + tid], a2);
          a3 = fmaf(su.u.sl.sGH[k+3], aw1[(6+k  )*128 + tid], a3);
        }
        su.u.sl.sBatt[tid] = ab1[tid] + ((a0+a1)+(a2+a3));
      }
      __syncthreads();
      int i = ch*NTHR + tid;
      bool act = i < N;
      float p0=0.f,p1=0.f,p2=0.f,s=-3.4e38f;
      if (act){
        const float* pp = canvas + (size_t)(b*NMAX + i)*3;
        p0=cld(pp); p1=cld(pp+1); p2=cld(pp+2);
        float s0=0.f,s1=0.f,s2=0.f,s3=0.f;
        for (int j=0;j<128;j+=4){
          float v0 = su.u.sl.sBatt[j  ] + p0*aw1[j  ] + p1*aw1[128+j  ] + p2*aw1[256+j  ];
          float v1 = su.u.sl.sBatt[j+1] + p0*aw1[j+1] + p1*aw1[128+j+1] + p2*aw1[256+j+1];
          float v2 = su.u.sl.sBatt[j+2] + p0*aw1[j+2] + p1*aw1[128+j+2] + p2*aw1[256+j+2];
          float v3 = su.u.sl.sBatt[j+3] + p0*aw1[j+3] + p1*aw1[128+j+3] + p2*aw1[256+j+3];
          s0 = fmaf(fmaxf(v0,0.f), aw2[j  ], s0);
          s1 = fmaf(fmaxf(v1,0.f), aw2[j+1], s1);
          s2 = fmaf(fmaxf(v2,0.f), aw2[j+2], s2);
          s3 = fmaf(fmaxf(v3,0.f), aw2[j+3], s3);
        }
        s = ab2[0] + ((s0+s1)+(s2+s3));
      }
      float mb = block_max(s, su.u.sl.red);
      float e = act ? expf(s - mb) : 0.f;
      float se = block_sum(e, su.u.sl.red);
      float wx = block_sum(e*p0, su.u.sl.red);
      float wy = block_sum(e*p1, su.u.sl.red);
      float wz = block_sum(e*p2, su.u.sl.red);
      if (tid==0){
        float* pr = partb + (size_t)(b*32 + ch)*8;
        cst(pr+0, mb); cst(pr+1, se); cst(pr+2, wx); cst(pr+3, wy); cst(pr+4, wz);
      }
    } else if (blk >= 252){
      int b = blk - 252;
      if (tid < GD+HD)
        su.u.sl.sGH[tid] = (tid < GD) ? dec_f(culd(&gmax[b*GD + tid]))
                                      : cld(&h_in[b*HD + (tid-GD)]);
      __syncthreads();
      {
        int o = tid;
        float g0=0.f,g1=0.f,g2=0.f,g3=0.f;
        for (int k=0;k<GD;k+=4){
          g0 = fmaf(su.u.sl.sGH[k  ], wih[(size_t)(k  )*512 + o], g0);
          g1 = fmaf(su.u.sl.sGH[k+1], wih[(size_t)(k+1)*512 + o], g1);
          g2 = fmaf(su.u.sl.sGH[k+2], wih[(size_t)(k+2)*512 + o], g2);
          g3 = fmaf(su.u.sl.sGH[k+3], wih[(size_t)(k+3)*512 + o], g3);
        }
        for (int k=0;k<HD;k+=4){
          g0 = fmaf(su.u.sl.sGH[GD+k  ], whh[(size_t)(k  )*512 + o], g0);
          g1 = fmaf(su.u.sl.sGH[GD+k+1], whh[(size_t)(k+1)*512 + o], g1);
          g2 = fmaf(su.u.sl.sGH[GD+k+2], whh[(size_t)(k+2)*512 + o], g2);
          g3 = fmaf(su.u.sl.sGH[GD+k+3], whh[(size_t)(k+3)*512 + o], g3);
        }
        cst(&gpre[b*512 + o], bih[o] + bhh[o] + ((g0+g1)+(g2+g3)));
      }
    }
    gsync();

    /* ---- stepA phase: center+top-K (blocks 0..3)
            + incremental chamfer in otherwise-idle blocks ---- */
    if (blk < 4){
      int b = blk;
      const float* cv = canvas + (size_t)b*NMAX*3;
      int lane = tid & 63, wid = tid >> 6;

      float pm=-3.4e38f, pse=0.f, pwx=0.f, pwy=0.f, pwz=0.f;
      if (tid < nch){
        const float* pp = partb + (size_t)(b*32 + tid)*8;
        pm=cld(pp); pse=cld(pp+1); pwx=cld(pp+2); pwy=cld(pp+3); pwz=cld(pp+4);
      }
      float M = block_max(pm, su.u.sa.red);
      float w = (tid < nch) ? expf(pm - M) : 0.f;
      float se = block_sum(pse*w, su.u.sa.red);
      float wx = block_sum(pwx*w, su.u.sa.red);
      float wy = block_sum(pwy*w, su.u.sa.red);
      float wz = block_sum(pwz*w, su.u.sa.red);
      if (tid==0){ su.u.sa.sC[0]=wx/se; su.u.sa.sC[1]=wy/se; su.u.sa.sC[2]=wz/se; }
      __syncthreads();
      float cx=su.u.sa.sC[0], cy=su.u.sa.sC[1], cz=su.u.sa.sC[2];
      if (tid<3) cst(&centerb[b*3+tid], su.u.sa.sC[tid]);

      unsigned ur[32];
#pragma unroll
      for (int q=0;q<32;q+=8){
        float px[8], py[8], pz[8];
#pragma unroll
        for (int r=0;r<8;r++){
          int i = tid + (q+r)*NTHR;
          int ic2 = (i < N) ? i : 0;
          const float* p = cv + (size_t)ic2*3;
          px[r]=cld(p); py[r]=cld(p+1); pz[r]=cld(p+2);
        }
#pragma unroll
        for (int r=0;r<8;r++){
          int i = tid + (q+r)*NTHR;
          ur[q+r] = 0xFFFFFFFFu;
          if (i < N){
            float dx=px[r]-cx, dy=py[r]-cy, dz=pz[r]-cz;
            ur[q+r] = __float_as_uint(dx*dx + dy*dy + dz*dz);
          }
        }
      }

      unsigned T = 0u;
      int cntBelow = 0;
      int par = 0;
      {
        unsigned cand = 1u<<30;
        unsigned tc = 0;
#pragma unroll
        for (int q=0;q<32;q++) tc += (ur[q] < cand) ? 1u : 0u;
#pragma unroll
        for (int s2=32;s2>0;s2>>=1) tc += __shfl_down(tc, s2, 64);
        if (lane==0) su.u.sa.cbufA[par][wid] = tc;
        __syncthreads();
        unsigned tot = 0;
#pragma unroll
        for (int i2=0;i2<8;i2++) tot += su.u.sa.cbufA[par][i2];
        if ((int)tot < KSEL){ T = cand; cntBelow = (int)tot; }
        par ^= 1;
      }
      for (int bit=29; bit>=1; bit-=2){
        unsigned q1 = 1u<<(bit-1);
        unsigned c1 = T + q1, c2 = T + 2u*q1, c3 = T + 3u*q1;
        unsigned ta = 0, tb = 0;
#pragma unroll
        for (int q=0;q<32;q++){
          unsigned u = ur[q];
          ta += (u < c1 ? 1u : 0u) | (u < c2 ? 0x10000u : 0u);
          tb += (u < c3 ? 1u : 0u);
        }
#pragma unroll
        for (int s2=32;s2>0;s2>>=1){ ta += __shfl_down(ta, s2, 64); tb += __shfl_down(tb, s2, 64); }
        if (lane==0){ su.u.sa.cbufA[par][wid] = ta; su.u.sa.cbufB[par][wid] = tb; }
        __syncthreads();
        unsigned sa2 = 0, sb2 = 0;
#pragma unroll
        for (int i2=0;i2<8;i2++){ sa2 += su.u.sa.cbufA[par][i2]; sb2 += su.u.sa.cbufB[par][i2]; }
        int n1 = (int)(sa2 & 0xFFFFu), n2 = (int)(sa2 >> 16), n3 = (int)sb2;
        if (n3 < KSEL){ T = c3; cntBelow = n3; }
        else if (n2 < KSEL){ T = c2; cntBelow = n2; }
        else if (n1 < KSEL){ T = c1; cntBelow = n1; }
        par ^= 1;
      }
      int kneed = KSEL - cntBelow;

      if (tid==0) su.u.sa.tieCnt = 0;
      __syncthreads();
      float sx=0.f, sy=0.f, sz=0.f;
#pragma unroll
      for (int q=0;q<32;q++){
        unsigned uu = ur[q];
        if (uu < T){
          const float* p = cv + (size_t)(tid + q*NTHR)*3;
          sx += cld(p); sy += cld(p+1); sz += cld(p+2);
        } else if (uu == T){
          int pos = atomicAdd(&su.u.sa.tieCnt, 1);
          if (pos < 256) su.u.sa.tieIdx[pos] = tid + q*NTHR;
        }
      }
      __syncthreads();
      sx = block_sum(sx, su.u.sa.red);
      sy = block_sum(sy, su.u.sa.red);
      sz = block_sum(sz, su.u.sa.red);
      if (tid==0){
        int mm = su.u.sa.tieCnt < 256 ? su.u.sa.tieCnt : 256;
        for (int tt=0; tt<kneed; tt++){
          int best=-1, bi=0x7fffffff;
          for (int q=0;q<mm;q++){ int v = su.u.sa.tieIdx[q]; if (v < bi){ bi=v; best=q; } }
          if (best >= 0){
            su.u.sa.tieIdx[best] = 0x7fffffff;
            const float* p = cv + (size_t)bi*3;
            sx += cld(p); sy += cld(p+1); sz += cld(p+2);
          }
        }
        cst(&centerb[16 + b*3 + 0], sx/KSEL - cx);
        cst(&centerb[16 + b*3 + 1], sy/KSEL - cy);
        cst(&centerb[16 + b*3 + 2], sz/KSEL - cz);
      }
    } else if (t == 0 && blk < 68){
      /* dir0: canvas[0..N0) -> gt. 64 blocks. */
      int rem = blk - 4;
      int b = rem >> 4, l = rem & 15, xb = l >> 2, yb = l & 3;
      chamfer_tile<2>(canvas + (size_t)b*NMAX*3, gt + ((size_t)b*N0 + yb*1024)*3,
                      minAB + b*N0, N0, xb*1024, 1024, true, false,
                      su.u.ch.sy0, su.u.ch.sy1, su.u.ch.sy2, su.u.ch.sny, tid);
    } else if (t >= 1 && blk < 20){
      /* dir2 incremental: new points of step t-1 -> gt. 16 blocks. */
      int rem = blk - 4;
      int b = rem >> 2, yb = rem & 3;
      chamfer_tile<3>(canvas + ((size_t)b*NMAX + N0 + (size_t)(t-1)*NEWP)*3,
                      gt + ((size_t)b*N0 + yb*1024)*3,
                      minCD + b*NNEW + (t-1)*NEWP, NEWP, 0, 1024, true, false,
                      su.u.ch.sy0, su.u.ch.sy1, su.u.ch.sy2, su.u.ch.sny, tid);
    }
    gsync();

    /* ---- REFDEC phase: LSTM finish + refine-decode + canvas append
            (blocks 0..11 = 3 bx x 4 b; no d-redundancy) ---- */
    if (blk < 12){
      int bx = blk >> 2, b = blk & 3;
      float cx = cld(&centerb[b*3+0]), cy = cld(&centerb[b*3+1]), cz = cld(&centerb[b*3+2]);
      float fx = cld(&centerb[16+b*3+0]), fy = cld(&centerb[16+b*3+1]), fz = cld(&centerb[16+b*3+2]);
      {
        int o = tid;
        float gg = cld(&gpre[b*512 + o]);
        gg += cx*wih[(size_t)256*512+o] + cy*wih[(size_t)257*512+o] + cz*wih[(size_t)258*512+o];
        gg += fx*wih[(size_t)259*512+o] + fy*wih[(size_t)260*512+o] + fz*wih[(size_t)261*512+o];
        su.u.re.sG[o] = gg;
      }
      __syncthreads();
      if (tid < HD){
        float gi=su.u.re.sG[tid], gf=su.u.re.sG[128+tid], gg2=su.u.re.sG[256+tid], go=su.u.re.sG[384+tid];
        float cn = sigm(gf)*cld(&c_in[b*HD+tid]) + sigm(gi)*tanhf(gg2);
        float hn = sigm(go)*tanhf(cn);
        su.u.re.sH[tid] = hn;
        if (bx==0){ cst(&c_out[b*HD+tid], cn); cst(&h_out[b*HD+tid], hn); }
      }
      __syncthreads();
      if (tid < HD){
        float a0=0.f,a1=0.f,a2=0.f,a3=0.f;
        for (int k=0;k<HD;k+=4){
          a0 = fmaf(su.u.re.sH[k  ], rw1[(k  )*HD + tid], a0);
          a1 = fmaf(su.u.re.sH[k+1], rw1[(k+1)*HD + tid], a1);
          a2 = fmaf(su.u.re.sH[k+2], rw1[(k+2)*HD + tid], a2);
          a3 = fmaf(su.u.re.sH[k+3], rw1[(k+3)*HD + tid], a3);
        }
        su.u.re.sRf[tid] = fmaxf(rb1[tid] + ((a0+a1)+(a2+a3)), 0.f);
      }
      __syncthreads();
      int i = bx*NTHR + tid;
      bool act = i < NEWP;
      int ic = act ? i : 0;
      float a0 = rb2[3*ic], a1 = rb2[3*ic+1], a2 = rb2[3*ic+2];
      for (int k=0;k<HD;k++){
        const float* wv = rw2 + (size_t)k*(NEWP*3) + 3*ic;
        float hk = su.u.re.sRf[k];
        a0 = fmaf(hk, wv[0], a0); a1 = fmaf(hk, wv[1], a1); a2 = fmaf(hk, wv[2], a2);
      }
      float p0 = fmaf(a0, 0.02f, cx), p1 = fmaf(a1, 0.02f, cy), p2 = fmaf(a2, 0.02f, cz);
      if (act){
        float* cp = canvas + ((size_t)b*NMAX + N + i)*3;
        cst(cp+0, p0); cst(cp+1, p1); cst(cp+2, p2);
      }
    }
    gsync();

    /* ---- ENCNEW phase (t < 9): enc slabs of the 1152 new points.
            72 blocks = 4 b x 18 slabs of 64. ---- */
    if (t < NSTEPS-1){
      if (blk < 72){
        int b = blk/18, slab = blk - b*18;
        enc_slab(canvas + ((size_t)b*NMAX + N + slab*64)*3, true,
                 w1, b1, w2, b2, w3, b3, &gmax[b*GD], f2l, tid);
      }
      gsync();
    }
  }

  /* ============ final chamfer: dir1 (128), dir3 (96), dir2-last (16) ==== */
  {
    if (blk < 128){
      int b = blk >> 5, l = blk & 31, xb = l >> 4, yb = l & 15;
      int tn = min(1024, NMAX - yb*1024);
      chamfer_tile<4>(gt + (size_t)b*N0*3, canvas + ((size_t)b*NMAX + yb*1024)*3,
                      minAB + BB*N0 + b*N0, N0, xb*2048, tn, false, true,
                      su.u.ch.sy0, su.u.ch.sy1, su.u.ch.sy2, su.u.ch.sny, tid);
    } else if (blk < 224){
      int rem = blk - 128;
      int b = rem/24, l = rem%24, xb = l/12, yb = l%12;
      int tn = min(1024, NNEW - yb*1024);
      chamfer_tile<4>(gt + (size_t)b*N0*3, canvas + ((size_t)b*NMAX + N0 + yb*1024)*3,
                      minCD + BB*NNEW + b*N0, N0, xb*2048, tn, false, true,
                      su.u.ch.sy0, su.u.ch.sy1, su.u.ch.sy2, su.u.ch.sny, tid);
    } else if (blk < 240){
      int rem = blk - 224;
      int b = rem >> 2, yb = rem & 3;
      chamfer_tile<3>(canvas + ((size_t)b*NMAX + N0 + (size_t)(NSTEPS-1)*NEWP)*3,
                      gt + ((size_t)b*N0 + yb*1024)*3,
                      minCD + b*NNEW + (NSTEPS-1)*NEWP, NEWP, 0, 1024, true, false,
                      su.u.ch.sy0, su.u.ch.sy1, su.u.ch.sy2, su.u.ch.sny, tid);
    }
  }
  gsync();

  /* ============ reduce (blocks 0..15) ============ */
  if (blk < 16){
    int s = blk, dir = s>>2, b = s&3;
    const unsigned* mp; int len;
    if (dir==0){      mp=minAB + b*N0;            len=N0; }
    else if (dir==1){ mp=minAB + BB*N0 + b*N0;    len=N0; }
    else if (dir==2){ mp=minCD + b*NNEW;          len=NNEW; }
    else {            mp=minCD + BB*NNEW + b*N0;  len=N0; }
    float v = 0.f;
    int i = tid;
    for (; i + 3*NTHR < len; i += 4*NTHR){
      unsigned u0=culd(mp+i), u1=culd(mp+i+NTHR), u2=culd(mp+i+2*NTHR), u3=culd(mp+i+3*NTHR);
      v += dec_f(u0); v += dec_f(u1); v += dec_f(u2); v += dec_f(u3);
    }
    for (; i < len; i += NTHR) v += dec_f(culd(mp+i));
    v = block_sum(v, su.u.rd.red);
    if (tid==0) cst(&acc[s], v);
  }
  gsync();

  /* ============ finish ============ */
  if (blk == 0 && tid == 0){
    float cd1 = 0.f, cd2 = 0.f;
    for (int b=0;b<BB;b++) cd1 += cld(&acc[b])/(float)N0 + cld(&acc[4+b])/(float)N0;
    for (int b=0;b<BB;b++) cd2 += cld(&acc[8+b])/(float)NNEW + cld(&acc[12+b])/(float)N0;
    out[0] = 0.1f*(cd1/BB) + 1.0f*(cd2/BB);
  }
}

extern "C" void kernel_launch(void* const* d_in, const int* in_sizes, int n_in,
                              void* d_out, int out_size, void* d_ws, size_t ws_size,
                              hipStream_t stream) {
  (void)in_sizes; (void)n_in; (void)out_size; (void)ws_size;
  const float* points   = (const float*)d_in[0];
  const float* gt       = (const float*)d_in[1];
  const float* enc_w1   = (const float*)d_in[2];
  const float* enc_b1   = (const float*)d_in[3];
  const float* enc_w2   = (const float*)d_in[4];
  const float* enc_b2   = (const float*)d_in[5];
  const float* enc_w3   = (const float*)d_in[6];
  const float* enc_b3   = (const float*)d_in[7];
  const float* att_w1   = (const float*)d_in[8];
  const float* att_b1   = (const float*)d_in[9];
  const float* att_w2   = (const float*)d_in[10];
  const float* att_b2   = (const float*)d_in[11];
  const float* lstm_wih = (const float*)d_in[12];
  const float* lstm_whh = (const float*)d_in[13];
  const float* lstm_bih = (const float*)d_in[14];
  const float* lstm_bhh = (const float*)d_in[15];
  const float* ref_w1   = (const float*)d_in[16];
  const float* ref_b1   = (const float*)d_in[17];
  const float* ref_w2   = (const float*)d_in[18];
  const float* ref_b2   = (const float*)d_in[19];
  float* out = (float*)d_out;
  float* ws  = (float*)d_ws;

  mega_kernel<<<dim3(NBLK), NTHR, 0, stream>>>(
      points, gt,
      enc_w1, enc_b1, enc_w2, enc_b2, enc_w3, enc_b3,
      att_w1, att_b1, att_w2, att_b2,
      lstm_wih, lstm_whh, lstm_bih, lstm_bhh,
      ref_w1, ref_b1, ref_w2, ref_b2,
      out, ws);
}

// Round 8
// 1865.438 us; speedup vs baseline: 1.7478x; 1.3754x over previous
//
#include <hip/hip_runtime.h>
#include <math.h>

#define BB 4
#define N0 4096
#define NEWP 1152
#define GD 256
#define HD 128
#define KSEL 64
#define NSTEPS 10
#define NMAX (N0 + NSTEPS*NEWP)   /* 15616 */
#define NNEW (NSTEPS*NEWP)        /* 11520 */

#define NBLK 256
#define NTHR 512

/* ---- workspace layout (float offsets) ---- */
#define OFF_CANVAS 0
#define OFF_MINAB  (OFF_CANVAS + BB*NMAX*3)
#define OFF_MINCD  (OFF_MINAB + 2*BB*N0)
#define OFF_GMAX   (OFF_MINCD + BB*NNEW + BB*N0)
#define OFF_H      (OFF_GMAX + BB*GD)
#define OFF_C      (OFF_H + 2*BB*HD)
#define OFF_ACC    (OFF_C + 2*BB*HD)
#define OFF_CENTER (OFF_ACC + 16)
#define OFF_PART   (OFF_CENTER + 32)
#define OFF_GPRE   (OFF_PART + BB*32*8)      /* 4*512 gate partials */

#define AGT __HIP_MEMORY_SCOPE_AGENT

/* coherent (cache-bypassing, IF-coherence-point) accessors for cross-block
   data. Weights/inputs keep normal cached loads. */
__device__ __forceinline__ float cld(const float* p){
  return __hip_atomic_load((float*)p, __ATOMIC_RELAXED, AGT);
}
__device__ __forceinline__ void cst(float* p, float v){
  __hip_atomic_store(p, v, __ATOMIC_RELAXED, AGT);
}
__device__ __forceinline__ unsigned culd(const unsigned* p){
  return __hip_atomic_load((unsigned*)p, __ATOMIC_RELAXED, AGT);
}
__device__ __forceinline__ void cust(unsigned* p, unsigned v){
  __hip_atomic_store(p, v, __ATOMIC_RELAXED, AGT);
}
__device__ __forceinline__ float ldc(const float* p, bool coh){
  return coh ? cld(p) : *p;
}

__device__ __forceinline__ unsigned enc_f(float f){
  unsigned u = __float_as_uint(f);
  return (u & 0x80000000u) ? ~u : (u | 0x80000000u);
}
__device__ __forceinline__ float dec_f(unsigned e){
  unsigned u = (e & 0x80000000u) ? (e & 0x7fffffffu) : ~e;
  return __uint_as_float(u);
}
__device__ __forceinline__ float sigm(float x){ return 1.f/(1.f+expf(-x)); }

__device__ __forceinline__ float block_sum(float v, volatile float* red){
#pragma unroll
  for (int s=32;s>0;s>>=1) v += __shfl_down(v, s, 64);
  int lane = threadIdx.x & 63, w = threadIdx.x >> 6, nw = blockDim.x >> 6;
  __syncthreads();
  if (lane==0) red[w] = v;
  __syncthreads();
  if (w==0){
    float x = (lane < nw) ? red[lane] : 0.f;
#pragma unroll
    for (int s=8;s>0;s>>=1) x += __shfl_down(x, s, 64);
    if (lane==0) red[0] = x;
  }
  __syncthreads();
  float r = red[0];
  __syncthreads();
  return r;
}
__device__ __forceinline__ float block_max(float v, volatile float* red){
#pragma unroll
  for (int s=32;s>0;s>>=1) v = fmaxf(v, __shfl_down(v, s, 64));
  int lane = threadIdx.x & 63, w = threadIdx.x >> 6, nw = blockDim.x >> 6;
  __syncthreads();
  if (lane==0) red[w] = v;
  __syncthreads();
  if (w==0){
    float x = (lane < nw) ? red[lane] : -3.4e38f;
#pragma unroll
    for (int s=8;s>0;s>>=1) x = fmaxf(x, __shfl_down(x, s, 64));
    if (lane==0) red[0] = x;
  }
  __syncthreads();
  float r = red[0];
  __syncthreads();
  return r;
}

/* ---- fence-free grid barrier: 2-level monotonic arrive/spin.
   s_sleep(32) backoff keeps spin fetch low (proven r4). ---- */
__device__ __align__(128) unsigned g_grp[256];   /* 8 counters, stride 32 */
__device__ __align__(128) unsigned g_root;
__device__ __align__(128) unsigned g_gen;

__device__ __forceinline__ void gsync(){
  __syncthreads();
  if (threadIdx.x == 0){
    unsigned snap = __hip_atomic_load(&g_gen, __ATOMIC_RELAXED, AGT);
    asm volatile("" ::: "memory");
    int g = blockIdx.x >> 5;
    unsigned od = __hip_atomic_fetch_add(&g_grp[g*32], 1u, __ATOMIC_RELAXED, AGT);
    bool done = false;
    if ((od & 31u) == 31u){
      unsigned rd = __hip_atomic_fetch_add(&g_root, 1u, __ATOMIC_RELAXED, AGT);
      if ((rd & 7u) == 7u){
        __hip_atomic_fetch_add(&g_gen, 1u, __ATOMIC_RELAXED, AGT);
        done = true;
      }
    }
    if (!done){
      while (__hip_atomic_load(&g_gen, __ATOMIC_RELAXED, AGT) == snap)
        __builtin_amdgcn_s_sleep(32);
    }
    asm volatile("" ::: "memory");
  }
  __syncthreads();
}

#define F1PAD 65    /* 64x65 f1 slab: conflict-free column access */
#define F2PAD 132   /* 64x132 f2 slab: 16B-aligned rows */

/* one shared-memory arena, aliased per phase (f1l lives here too:
   it is only live inside enc_slab, which uses no other SU member) */
struct alignas(16) SU {
  union {
    struct { float sy0[1024], sy1[1024], sy2[1024], sny[1024]; } ch;
    struct { float sBatt[128]; float sGH[GD+HD]; float red[16]; } sl;
    struct { float red[16]; float sC[3]; unsigned cbufA[2][8]; unsigned cbufB[2][8];
             int tieCnt; int tieIdx[256]; } sa;
    struct { float sG[512]; float sH[HD]; float sRf[HD]; } re;
    struct { float red[16]; } rd;
    float f1l[64*F1PAD];
  } u;
};

/* LDS-cooperative enc slab, SPILL-FREE version: f1 lives in LDS, never in
   registers (r6/r7 kept f1[64] in regs while streaming divergently-addressed
   w2 values -> >150 live regs -> scratch; that was the 300-600MB WRITE).
   A0: thread (p=tid&63, kc=tid>>6) computes f1[kc*8..+8] -> f1l[p][j]
       (stride 65: conflict-free). ~15 regs.
   A1: thread (p,kc) computes f2[k0..k0+16]: per j one ds_read f1l[p][j]
       (2-way = free) + 16 indep FMA; unroll 2 caps live w2 at 32. ~60 regs.
   B:  thread (d0=4*(tid&63), pg=tid>>6): acc[8][4]; k-steps of 4: coalesced
       float4 w3 rows + broadcast float4 f2l reads -> 16 FMA/LDS-read. ~60 regs.
   Summation orders bitwise-match reference (f1 formula; f2 j=0..63 asc;
   f3 k=0..127 asc from b3; max-pool order-independent). */
__device__ __forceinline__ void enc_slab(
    const float* __restrict__ pts, bool coh,
    const float* __restrict__ w1, const float* __restrict__ b1,
    const float* __restrict__ w2, const float* __restrict__ b2,
    const float* __restrict__ w3, const float* __restrict__ b3,
    unsigned* __restrict__ gmaxrow, float* __restrict__ f1l,
    float* __restrict__ f2l, int tid)
{
  int p = tid & 63, kc = tid >> 6;
  {
    const float* pp = pts + (size_t)p*3;
    float p0 = ldc(pp,coh), p1 = ldc(pp+1,coh), p2 = ldc(pp+2,coh);
    int j0 = kc*8;
#pragma unroll
    for (int jj=0;jj<8;jj++){
      int j = j0 + jj;
      f1l[p*F1PAD + j] = fmaxf(0.f, b1[j] + p0*w1[j] + p1*w1[64+j] + p2*w1[128+j]);
    }
  }
  __syncthreads();
  {
    int k0 = kc*16;
    float sacc[16];
#pragma unroll
    for (int kk=0;kk<16;kk++) sacc[kk] = b2[k0+kk];
#pragma unroll 2
    for (int j=0;j<64;j++){
      float fj = f1l[p*F1PAD + j];
      const float* wr = w2 + j*128 + k0;
#pragma unroll
      for (int kk=0;kk<16;kk++) sacc[kk] = fmaf(fj, wr[kk], sacc[kk]);
    }
#pragma unroll
    for (int kk=0;kk<16;kk++) f2l[p*F2PAD + k0 + kk] = fmaxf(sacc[kk], 0.f);
  }
  __syncthreads();
  {
    int dq = tid & 63, pg = tid >> 6;
    int d0 = dq*4;
    float acc[8][4];
#pragma unroll
    for (int q=0;q<8;q++)
#pragma unroll
      for (int j=0;j<4;j++) acc[q][j] = b3[d0+j];
#pragma unroll 1
    for (int ks=0;ks<32;ks++){
      int k = ks*4;
      float4 wv0 = *(const float4*)&w3[(size_t)(k+0)*256 + d0];
      float4 wv1 = *(const float4*)&w3[(size_t)(k+1)*256 + d0];
      float4 wv2 = *(const float4*)&w3[(size_t)(k+2)*256 + d0];
      float4 wv3 = *(const float4*)&w3[(size_t)(k+3)*256 + d0];
      const float* w0p = (const float*)&wv0;
      const float* w1p = (const float*)&wv1;
      const float* w2p = (const float*)&wv2;
      const float* w3p = (const float*)&wv3;
#pragma unroll
      for (int q=0;q<8;q++){
        float4 f = *(const float4*)&f2l[(pg*8+q)*F2PAD + k];  /* broadcast */
#pragma unroll
        for (int j=0;j<4;j++){
          float a = acc[q][j];
          a = fmaf(f.x, w0p[j], a);
          a = fmaf(f.y, w1p[j], a);
          a = fmaf(f.z, w2p[j], a);
          a = fmaf(f.w, w3p[j], a);
          acc[q][j] = a;
        }
      }
    }
#pragma unroll
    for (int j=0;j<4;j++){
      float m = acc[0][j];
#pragma unroll
      for (int q=1;q<8;q++) m = fmaxf(m, acc[q][j]);
      atomicMax(&gmaxrow[d0+j], enc_f(m));
    }
  }
}

/* one chamfer tile; min chain split in two (min is order-independent) */
template<int QN>
__device__ __forceinline__ void chamfer_tile(
    const float* X, const float* Y, unsigned* mp,
    int Nx, int xbase, int tn, bool xcv, bool ycv,
    float* sy0, float* sy1, float* sy2, float* sny, int tid)
{
  for (int tt=tid; tt<tn; tt+=NTHR){
    const float* yp = Y + (size_t)tt*3;
    float y0=ldc(yp,ycv), y1=ldc(yp+1,ycv), y2=ldc(yp+2,ycv);
    sy0[tt]=-2.f*y0; sy1[tt]=-2.f*y1; sy2[tt]=-2.f*y2;
    sny[tt]=y0*y0+y1*y1+y2*y2;
  }
  __syncthreads();
  float X0[QN],X1[QN],X2[QN],NXr[QN],MNa[QN],MNb[QN]; int XI[QN]; bool VA[QN];
#pragma unroll
  for (int q=0;q<QN;q++){
    int x = xbase + q*NTHR + tid;
    VA[q] = x < Nx;
    int xc = VA[q] ? x : 0;
    const float* xp = X + (size_t)xc*3;
    X0[q]=ldc(xp,xcv); X1[q]=ldc(xp+1,xcv); X2[q]=ldc(xp+2,xcv);
    NXr[q] = X0[q]*X0[q] + X1[q]*X1[q] + X2[q]*X2[q];
    MNa[q] = 3.4e38f; MNb[q] = 3.4e38f; XI[q] = xc;
  }
  const float4* v0 = (const float4*)sy0;
  const float4* v1 = (const float4*)sy1;
  const float4* v2 = (const float4*)sy2;
  const float4* vn = (const float4*)sny;
  int j4n = tn >> 2;
  for (int j=0;j<j4n;j++){
    float4 a0 = v0[j], a1 = v1[j], a2 = v2[j], an = vn[j];
#pragma unroll
    for (int e=0;e<4;e++){
      float y0 = ((const float*)&a0)[e];
      float y1 = ((const float*)&a1)[e];
      float y2 = ((const float*)&a2)[e];
      float ny = ((const float*)&an)[e];
#pragma unroll
      for (int q=0;q<QN;q++){
        float d = fmaf(X0[q], y0, fmaf(X1[q], y1, fmaf(X2[q], y2, ny)));
        if (e & 1) MNb[q] = fminf(MNb[q], d);
        else       MNa[q] = fminf(MNa[q], d);
      }
    }
  }
  for (int j=j4n*4; j<tn; j++){
    float y0=sy0[j], y1=sy1[j], y2=sy2[j], ny=sny[j];
#pragma unroll
    for (int q=0;q<QN;q++){
      float d = fmaf(X0[q], y0, fmaf(X1[q], y1, fmaf(X2[q], y2, ny)));
      MNa[q] = fminf(MNa[q], d);
    }
  }
#pragma unroll
  for (int q=0;q<QN;q++)
    if (VA[q]) atomicMin(&mp[XI[q]], enc_f(fminf(MNa[q], MNb[q]) + NXr[q]));
}

__global__ __attribute__((amdgpu_flat_work_group_size(NTHR,NTHR), amdgpu_waves_per_eu(2,2)))
void mega_kernel(
    const float* __restrict__ points, const float* __restrict__ gt,
    const float* __restrict__ w1,  const float* __restrict__ b1,
    const float* __restrict__ w2,  const float* __restrict__ b2,
    const float* __restrict__ w3,  const float* __restrict__ b3,
    const float* __restrict__ aw1, const float* __restrict__ ab1,
    const float* __restrict__ aw2, const float* __restrict__ ab2,
    const float* __restrict__ wih, const float* __restrict__ whh,
    const float* __restrict__ bih, const float* __restrict__ bhh,
    const float* __restrict__ rw1, const float* __restrict__ rb1,
    const float* __restrict__ rw2, const float* __restrict__ rb2,
    float* __restrict__ out, float* __restrict__ ws)
{
  __shared__ SU su;
  __shared__ float f2l[64*F2PAD];     /* 33 KB enc slab */
  const int tid = threadIdx.x;
  const int blk = blockIdx.x;

  float* canvas   = ws + OFF_CANVAS;
  unsigned* minAB = (unsigned*)(ws + OFF_MINAB);
  unsigned* minCD = (unsigned*)(ws + OFF_MINCD);
  unsigned* gmax  = (unsigned*)(ws + OFF_GMAX);
  float* hb       = ws + OFF_H;
  float* cb       = ws + OFF_C;
  float* acc      = ws + OFF_ACC;
  float* centerb  = ws + OFF_CENTER;
  float* partb    = ws + OFF_PART;
  float* gpre     = ws + OFF_GPRE;

  /* ============ P0: init ============ */
  {
    int gid = blk*NTHR + tid;
    if (gid < BB*N0*3){
      int b = gid/(N0*3), r = gid - b*(N0*3);
      cst(&canvas[(size_t)b*NMAX*3 + r], points[gid]);
    }
    if (gid < 2*BB*N0) cust(&minAB[gid], 0xFFFFFFFFu);
    if (gid < BB*NNEW + BB*N0) cust(&minCD[gid], 0xFFFFFFFFu);
    if (gid < BB*GD) cust(&gmax[gid], 0u);
    if (gid < 2*BB*HD){ cst(&hb[gid], 0.f); cst(&cb[gid], 0.f); }
  }
  gsync();

  /* ============ P1: enc slabs of the 16384 initial points.
     256 blocks = 4 b x 64 slabs of 64 points. No redundancy. ============ */
  {
    int b = blk >> 6, slab = blk & 63;
    enc_slab(points + (size_t)(b*N0 + slab*64)*3, false,
             w1, b1, w2, b2, w3, b3, &gmax[b*GD], su.u.f1l, f2l, tid);
  }
  gsync();

  /* ============ 10-step loop ============ */
  for (int t=0; t<NSTEPS; t++){
    int N   = N0 + t*NEWP;
    int nch = (N + 511) >> 9;          /* chunks of 512, max 29 */
    float* h_in  = hb + (t&1)*BB*HD;
    float* h_out = hb + ((t+1)&1)*BB*HD;
    float* c_in  = cb + (t&1)*BB*HD;
    float* c_out = cb + ((t+1)&1)*BB*HD;

    /* ---- SL phase: attention partials (blocks 0..4nch-1, <=116)
            + LSTM gate precompute (blocks 252..255) ---- */
    if (blk < 4*nch){
      int b = blk / nch, ch = blk - b*nch;
      if (tid < GD+HD)
        su.u.sl.sGH[tid] = (tid < GD) ? dec_f(culd(&gmax[b*GD + tid]))
                                      : cld(&h_in[b*HD + (tid-GD)]);
      __syncthreads();
      if (tid < 128){
        float a0=0.f,a1=0.f,a2=0.f,a3=0.f;
        for (int k=0;k<GD+HD;k+=4){
          a0 = fmaf(su.u.sl.sGH[k  ], aw1[(3+k  )*128 + tid], a0);
          a1 = fmaf(su.u.sl.sGH[k+1], aw1[(4+k  )*128 + tid], a1);
          a2 = fmaf(su.u.sl.sGH[k+2], aw1[(5+k  )*128 + tid], a2);
          a3 = fmaf(su.u.sl.sGH[k+3], aw1[(6+k  )*128 + tid], a3);
        }
        su.u.sl.sBatt[tid] = ab1[tid] + ((a0+a1)+(a2+a3));
      }
      __syncthreads();
      int i = ch*NTHR + tid;
      bool act = i < N;
      float p0=0.f,p1=0.f,p2=0.f,s=-3.4e38f;
      if (act){
        const float* pp = canvas + (size_t)(b*NMAX + i)*3;
        p0=cld(pp); p1=cld(pp+1); p2=cld(pp+2);
        float s0=0.f,s1=0.f,s2=0.f,s3=0.f;
        for (int j=0;j<128;j+=4){
          float v0 = su.u.sl.sBatt[j  ] + p0*aw1[j  ] + p1*aw1[128+j  ] + p2*aw1[256+j  ];
          float v1 = su.u.sl.sBatt[j+1] + p0*aw1[j+1] + p1*aw1[128+j+1] + p2*aw1[256+j+1];
          float v2 = su.u.sl.sBatt[j+2] + p0*aw1[j+2] + p1*aw1[128+j+2] + p2*aw1[256+j+2];
          float v3 = su.u.sl.sBatt[j+3] + p0*aw1[j+3] + p1*aw1[128+j+3] + p2*aw1[256+j+3];
          s0 = fmaf(fmaxf(v0,0.f), aw2[j  ], s0);
          s1 = fmaf(fmaxf(v1,0.f), aw2[j+1], s1);
          s2 = fmaf(fmaxf(v2,0.f), aw2[j+2], s2);
          s3 = fmaf(fmaxf(v3,0.f), aw2[j+3], s3);
        }
        s = ab2[0] + ((s0+s1)+(s2+s3));
      }
      float mb = block_max(s, su.u.sl.red);
      float e = act ? expf(s - mb) : 0.f;
      float se = block_sum(e, su.u.sl.red);
      float wx = block_sum(e*p0, su.u.sl.red);
      float wy = block_sum(e*p1, su.u.sl.red);
      float wz = block_sum(e*p2, su.u.sl.red);
      if (tid==0){
        float* pr = partb + (size_t)(b*32 + ch)*8;
        cst(pr+0, mb); cst(pr+1, se); cst(pr+2, wx); cst(pr+3, wy); cst(pr+4, wz);
      }
    } else if (blk >= 252){
      int b = blk - 252;
      if (tid < GD+HD)
        su.u.sl.sGH[tid] = (tid < GD) ? dec_f(culd(&gmax[b*GD + tid]))
                                      : cld(&h_in[b*HD + (tid-GD)]);
      __syncthreads();
      {
        int o = tid;
        float g0=0.f,g1=0.f,g2=0.f,g3=0.f;
        for (int k=0;k<GD;k+=4){
          g0 = fmaf(su.u.sl.sGH[k  ], wih[(size_t)(k  )*512 + o], g0);
          g1 = fmaf(su.u.sl.sGH[k+1], wih[(size_t)(k+1)*512 + o], g1);
          g2 = fmaf(su.u.sl.sGH[k+2], wih[(size_t)(k+2)*512 + o], g2);
          g3 = fmaf(su.u.sl.sGH[k+3], wih[(size_t)(k+3)*512 + o], g3);
        }
        for (int k=0;k<HD;k+=4){
          g0 = fmaf(su.u.sl.sGH[GD+k  ], whh[(size_t)(k  )*512 + o], g0);
          g1 = fmaf(su.u.sl.sGH[GD+k+1], whh[(size_t)(k+1)*512 + o], g1);
          g2 = fmaf(su.u.sl.sGH[GD+k+2], whh[(size_t)(k+2)*512 + o], g2);
          g3 = fmaf(su.u.sl.sGH[GD+k+3], whh[(size_t)(k+3)*512 + o], g3);
        }
        cst(&gpre[b*512 + o], bih[o] + bhh[o] + ((g0+g1)+(g2+g3)));
      }
    }
    gsync();

    /* ---- stepA phase: center+top-K (blocks 0..3)
            + incremental chamfer in otherwise-idle blocks ---- */
    if (blk < 4){
      int b = blk;
      const float* cv = canvas + (size_t)b*NMAX*3;
      int lane = tid & 63, wid = tid >> 6;

      float pm=-3.4e38f, pse=0.f, pwx=0.f, pwy=0.f, pwz=0.f;
      if (tid < nch){
        const float* pp = partb + (size_t)(b*32 + tid)*8;
        pm=cld(pp); pse=cld(pp+1); pwx=cld(pp+2); pwy=cld(pp+3); pwz=cld(pp+4);
      }
      float M = block_max(pm, su.u.sa.red);
      float w = (tid < nch) ? expf(pm - M) : 0.f;
      float se = block_sum(pse*w, su.u.sa.red);
      float wx = block_sum(pwx*w, su.u.sa.red);
      float wy = block_sum(pwy*w, su.u.sa.red);
      float wz = block_sum(pwz*w, su.u.sa.red);
      if (tid==0){ su.u.sa.sC[0]=wx/se; su.u.sa.sC[1]=wy/se; su.u.sa.sC[2]=wz/se; }
      __syncthreads();
      float cx=su.u.sa.sC[0], cy=su.u.sa.sC[1], cz=su.u.sa.sC[2];
      if (tid<3) cst(&centerb[b*3+tid], su.u.sa.sC[tid]);

      unsigned ur[32];
#pragma unroll
      for (int q=0;q<32;q+=8){
        float px[8], py[8], pz[8];
#pragma unroll
        for (int r=0;r<8;r++){
          int i = tid + (q+r)*NTHR;
          int ic2 = (i < N) ? i : 0;
          const float* p = cv + (size_t)ic2*3;
          px[r]=cld(p); py[r]=cld(p+1); pz[r]=cld(p+2);
        }
#pragma unroll
        for (int r=0;r<8;r++){
          int i = tid + (q+r)*NTHR;
          ur[q+r] = 0xFFFFFFFFu;
          if (i < N){
            float dx=px[r]-cx, dy=py[r]-cy, dz=pz[r]-cz;
            ur[q+r] = __float_as_uint(dx*dx + dy*dy + dz*dz);
          }
        }
      }

      unsigned T = 0u;
      int cntBelow = 0;
      int par = 0;
      {
        unsigned cand = 1u<<30;
        unsigned tc = 0;
#pragma unroll
        for (int q=0;q<32;q++) tc += (ur[q] < cand) ? 1u : 0u;
#pragma unroll
        for (int s2=32;s2>0;s2>>=1) tc += __shfl_down(tc, s2, 64);
        if (lane==0) su.u.sa.cbufA[par][wid] = tc;
        __syncthreads();
        unsigned tot = 0;
#pragma unroll
        for (int i2=0;i2<8;i2++) tot += su.u.sa.cbufA[par][i2];
        if ((int)tot < KSEL){ T = cand; cntBelow = (int)tot; }
        par ^= 1;
      }
      for (int bit=29; bit>=1; bit-=2){
        unsigned q1 = 1u<<(bit-1);
        unsigned c1 = T + q1, c2 = T + 2u*q1, c3 = T + 3u*q1;
        unsigned ta = 0, tb = 0;
#pragma unroll
        for (int q=0;q<32;q++){
          unsigned u = ur[q];
          ta += (u < c1 ? 1u : 0u) | (u < c2 ? 0x10000u : 0u);
          tb += (u < c3 ? 1u : 0u);
        }
#pragma unroll
        for (int s2=32;s2>0;s2>>=1){ ta += __shfl_down(ta, s2, 64); tb += __shfl_down(tb, s2, 64); }
        if (lane==0){ su.u.sa.cbufA[par][wid] = ta; su.u.sa.cbufB[par][wid] = tb; }
        __syncthreads();
        unsigned sa2 = 0, sb2 = 0;
#pragma unroll
        for (int i2=0;i2<8;i2++){ sa2 += su.u.sa.cbufA[par][i2]; sb2 += su.u.sa.cbufB[par][i2]; }
        int n1 = (int)(sa2 & 0xFFFFu), n2 = (int)(sa2 >> 16), n3 = (int)sb2;
        if (n3 < KSEL){ T = c3; cntBelow = n3; }
        else if (n2 < KSEL){ T = c2; cntBelow = n2; }
        else if (n1 < KSEL){ T = c1; cntBelow = n1; }
        par ^= 1;
      }
      int kneed = KSEL - cntBelow;

      if (tid==0) su.u.sa.tieCnt = 0;
      __syncthreads();
      float sx=0.f, sy=0.f, sz=0.f;
#pragma unroll
      for (int q=0;q<32;q++){
        unsigned uu = ur[q];
        if (uu < T){
          const float* p = cv + (size_t)(tid + q*NTHR)*3;
          sx += cld(p); sy += cld(p+1); sz += cld(p+2);
        } else if (uu == T){
          int pos = atomicAdd(&su.u.sa.tieCnt, 1);
          if (pos < 256) su.u.sa.tieIdx[pos] = tid + q*NTHR;
        }
      }
      __syncthreads();
      sx = block_sum(sx, su.u.sa.red);
      sy = block_sum(sy, su.u.sa.red);
      sz = block_sum(sz, su.u.sa.red);
      if (tid==0){
        int mm = su.u.sa.tieCnt < 256 ? su.u.sa.tieCnt : 256;
        for (int tt=0; tt<kneed; tt++){
          int best=-1, bi=0x7fffffff;
          for (int q=0;q<mm;q++){ int v = su.u.sa.tieIdx[q]; if (v < bi){ bi=v; best=q; } }
          if (best >= 0){
            su.u.sa.tieIdx[best] = 0x7fffffff;
            const float* p = cv + (size_t)bi*3;
            sx += cld(p); sy += cld(p+1); sz += cld(p+2);
          }
        }
        cst(&centerb[16 + b*3 + 0], sx/KSEL - cx);
        cst(&centerb[16 + b*3 + 1], sy/KSEL - cy);
        cst(&centerb[16 + b*3 + 2], sz/KSEL - cz);
      }
    } else if (t == 0 && blk < 68){
      /* dir0: canvas[0..N0) -> gt. 64 blocks. */
      int rem = blk - 4;
      int b = rem >> 4, l = rem & 15, xb = l >> 2, yb = l & 3;
      chamfer_tile<2>(canvas + (size_t)b*NMAX*3, gt + ((size_t)b*N0 + yb*1024)*3,
                      minAB + b*N0, N0, xb*1024, 1024, true, false,
                      su.u.ch.sy0, su.u.ch.sy1, su.u.ch.sy2, su.u.ch.sny, tid);
    } else if (t >= 1 && blk < 20){
      /* dir2 incremental: new points of step t-1 -> gt. 16 blocks. */
      int rem = blk - 4;
      int b = rem >> 2, yb = rem & 3;
      chamfer_tile<3>(canvas + ((size_t)b*NMAX + N0 + (size_t)(t-1)*NEWP)*3,
                      gt + ((size_t)b*N0 + yb*1024)*3,
                      minCD + b*NNEW + (t-1)*NEWP, NEWP, 0, 1024, true, false,
                      su.u.ch.sy0, su.u.ch.sy1, su.u.ch.sy2, su.u.ch.sny, tid);
    }
    gsync();

    /* ---- REFDEC phase: LSTM finish + refine-decode + canvas append
            (blocks 0..11 = 3 bx x 4 b; no d-redundancy) ---- */
    if (blk < 12){
      int bx = blk >> 2, b = blk & 3;
      float cx = cld(&centerb[b*3+0]), cy = cld(&centerb[b*3+1]), cz = cld(&centerb[b*3+2]);
      float fx = cld(&centerb[16+b*3+0]), fy = cld(&centerb[16+b*3+1]), fz = cld(&centerb[16+b*3+2]);
      {
        int o = tid;
        float gg = cld(&gpre[b*512 + o]);
        gg += cx*wih[(size_t)256*512+o] + cy*wih[(size_t)257*512+o] + cz*wih[(size_t)258*512+o];
        gg += fx*wih[(size_t)259*512+o] + fy*wih[(size_t)260*512+o] + fz*wih[(size_t)261*512+o];
        su.u.re.sG[o] = gg;
      }
      __syncthreads();
      if (tid < HD){
        float gi=su.u.re.sG[tid], gf=su.u.re.sG[128+tid], gg2=su.u.re.sG[256+tid], go=su.u.re.sG[384+tid];
        float cn = sigm(gf)*cld(&c_in[b*HD+tid]) + sigm(gi)*tanhf(gg2);
        float hn = sigm(go)*tanhf(cn);
        su.u.re.sH[tid] = hn;
        if (bx==0){ cst(&c_out[b*HD+tid], cn); cst(&h_out[b*HD+tid], hn); }
      }
      __syncthreads();
      if (tid < HD){
        float a0=0.f,a1=0.f,a2=0.f,a3=0.f;
        for (int k=0;k<HD;k+=4){
          a0 = fmaf(su.u.re.sH[k  ], rw1[(k  )*HD + tid], a0);
          a1 = fmaf(su.u.re.sH[k+1], rw1[(k+1)*HD + tid], a1);
          a2 = fmaf(su.u.re.sH[k+2], rw1[(k+2)*HD + tid], a2);
          a3 = fmaf(su.u.re.sH[k+3], rw1[(k+3)*HD + tid], a3);
        }
        su.u.re.sRf[tid] = fmaxf(rb1[tid] + ((a0+a1)+(a2+a3)), 0.f);
      }
      __syncthreads();
      int i = bx*NTHR + tid;
      bool act = i < NEWP;
      int ic = act ? i : 0;
      float a0 = rb2[3*ic], a1 = rb2[3*ic+1], a2 = rb2[3*ic+2];
      for (int k=0;k<HD;k++){
        const float* wv = rw2 + (size_t)k*(NEWP*3) + 3*ic;
        float hk = su.u.re.sRf[k];
        a0 = fmaf(hk, wv[0], a0); a1 = fmaf(hk, wv[1], a1); a2 = fmaf(hk, wv[2], a2);
      }
      float p0 = fmaf(a0, 0.02f, cx), p1 = fmaf(a1, 0.02f, cy), p2 = fmaf(a2, 0.02f, cz);
      if (act){
        float* cp = canvas + ((size_t)b*NMAX + N + i)*3;
        cst(cp+0, p0); cst(cp+1, p1); cst(cp+2, p2);
      }
    }
    gsync();

    /* ---- ENCNEW phase (t < 9): enc slabs of the 1152 new points.
            72 blocks = 4 b x 18 slabs of 64. ---- */
    if (t < NSTEPS-1){
      if (blk < 72){
        int b = blk/18, slab = blk - b*18;
        enc_slab(canvas + ((size_t)b*NMAX + N + slab*64)*3, true,
                 w1, b1, w2, b2, w3, b3, &gmax[b*GD], su.u.f1l, f2l, tid);
      }
      gsync();
    }
  }

  /* ============ final chamfer: dir1 (128), dir3 (96), dir2-last (16) ==== */
  {
    if (blk < 128){
      int b = blk >> 5, l = blk & 31, xb = l >> 4, yb = l & 15;
      int tn = min(1024, NMAX - yb*1024);
      chamfer_tile<4>(gt + (size_t)b*N0*3, canvas + ((size_t)b*NMAX + yb*1024)*3,
                      minAB + BB*N0 + b*N0, N0, xb*2048, tn, false, true,
                      su.u.ch.sy0, su.u.ch.sy1, su.u.ch.sy2, su.u.ch.sny, tid);
    } else if (blk < 224){
      int rem = blk - 128;
      int b = rem/24, l = rem%24, xb = l/12, yb = l%12;
      int tn = min(1024, NNEW - yb*1024);
      chamfer_tile<4>(gt + (size_t)b*N0*3, canvas + ((size_t)b*NMAX + N0 + yb*1024)*3,
                      minCD + BB*NNEW + b*N0, N0, xb*2048, tn, false, true,
                      su.u.ch.sy0, su.u.ch.sy1, su.u.ch.sy2, su.u.ch.sny, tid);
    } else if (blk < 240){
      int rem = blk - 224;
      int b = rem >> 2, yb = rem & 3;
      chamfer_tile<3>(canvas + ((size_t)b*NMAX + N0 + (size_t)(NSTEPS-1)*NEWP)*3,
                      gt + ((size_t)b*N0 + yb*1024)*3,
                      minCD + b*NNEW + (NSTEPS-1)*NEWP, NEWP, 0, 1024, true, false,
                      su.u.ch.sy0, su.u.ch.sy1, su.u.ch.sy2, su.u.ch.sny, tid);
    }
  }
  gsync();

  /* ============ reduce (blocks 0..15) ============ */
  if (blk < 16){
    int s = blk, dir = s>>2, b = s&3;
    const unsigned* mp; int len;
    if (dir==0){      mp=minAB + b*N0;            len=N0; }
    else if (dir==1){ mp=minAB + BB*N0 + b*N0;    len=N0; }
    else if (dir==2){ mp=minCD + b*NNEW;          len=NNEW; }
    else {            mp=minCD + BB*NNEW + b*N0;  len=N0; }
    float v = 0.f;
    int i = tid;
    for (; i + 3*NTHR < len; i += 4*NTHR){
      unsigned u0=culd(mp+i), u1=culd(mp+i+NTHR), u2=culd(mp+i+2*NTHR), u3=culd(mp+i+3*NTHR);
      v += dec_f(u0); v += dec_f(u1); v += dec_f(u2); v += dec_f(u3);
    }
    for (; i < len; i += NTHR) v += dec_f(culd(mp+i));
    v = block_sum(v, su.u.rd.red);
    if (tid==0) cst(&acc[s], v);
  }
  gsync();

  /* ============ finish ============ */
  if (blk == 0 && tid == 0){
    float cd1 = 0.f, cd2 = 0.f;
    for (int b=0;b<BB;b++) cd1 += cld(&acc[b])/(float)N0 + cld(&acc[4+b])/(float)N0;
    for (int b=0;b<BB;b++) cd2 += cld(&acc[8+b])/(float)NNEW + cld(&acc[12+b])/(float)N0;
    out[0] = 0.1f*(cd1/BB) + 1.0f*(cd2/BB);
  }
}

extern "C" void kernel_launch(void* const* d_in, const int* in_sizes, int n_in,
                              void* d_out, int out_size, void* d_ws, size_t ws_size,
                              hipStream_t stream) {
  (void)in_sizes; (void)n_in; (void)out_size; (void)ws_size;
  const float* points   = (const float*)d_in[0];
  const float* gt       = (const float*)d_in[1];
  const float* enc_w1   = (const float*)d_in[2];
  const float* enc_b1   = (const float*)d_in[3];
  const float* enc_w2   = (const float*)d_in[4];
  const float* enc_b2   = (const float*)d_in[5];
  const float* enc_w3   = (const float*)d_in[6];
  const float* enc_b3   = (const float*)d_in[7];
  const float* att_w1   = (const float*)d_in[8];
  const float* att_b1   = (const float*)d_in[9];
  const float* att_w2   = (const float*)d_in[10];
  const float* att_b2   = (const float*)d_in[11];
  const float* lstm_wih = (const float*)d_in[12];
  const float* lstm_whh = (const float*)d_in[13];
  const float* lstm_bih = (const float*)d_in[14];
  const float* lstm_bhh = (const float*)d_in[15];
  const float* ref_w1   = (const float*)d_in[16];
  const float* ref_b1   = (const float*)d_in[17];
  const float* ref_w2   = (const float*)d_in[18];
  const float* ref_b2   = (const float*)d_in[19];
  float* out = (float*)d_out;
  float* ws  = (float*)d_ws;

  mega_kernel<<<dim3(NBLK), NTHR, 0, stream>>>(
      points, gt,
      enc_w1, enc_b1, enc_w2, enc_b2, enc_w3, enc_b3,
      att_w1, att_b1, att_w2, att_b2,
      lstm_wih, lstm_whh, lstm_bih, lstm_bhh,
      ref_w1, ref_b1, ref_w2, ref_b2,
      out, ws);
}